// Round 4
// baseline (2598.340 us; speedup 1.0000x reference)
//
#include <hip/hip_runtime.h>
#include <hip/hip_bf16.h>

__device__ __forceinline__ float4 f4zero() { return make_float4(0.f, 0.f, 0.f, 0.f); }

__device__ __forceinline__ void fma4(float4& a, float s, const float4& wv) {
    a.x = fmaf(s, wv.x, a.x);
    a.y = fmaf(s, wv.y, a.y);
    a.z = fmaf(s, wv.z, a.z);
    a.w = fmaf(s, wv.w, a.w);
}

// ---------------- encode: h = relu(X[M,32] @ W[32,128] + b) ----------------
__global__ __launch_bounds__(256) void encode_nodes_kernel(
    const float* __restrict__ X, const float* __restrict__ W,
    const float* __restrict__ bias, float* __restrict__ out, int M)
{
    __shared__ float w[32 * 128];
    __shared__ float xs[2][32];
    const int tid = threadIdx.x;
    const int j = tid & 127;
    const int slot = tid >> 7;
    for (int idx = tid; idx < 32 * 128; idx += 256) w[idx] = W[idx];
    __syncthreads();
    const float bj = bias[j];
    for (int r0 = blockIdx.x * 2; r0 < M; r0 += gridDim.x * 2) {
        const int r = r0 + slot;
        const bool valid = r < M;
        if (valid && j < 32) xs[slot][j] = X[(size_t)r * 32 + j];
        __syncthreads();
        if (valid) {
            float a = bj;
#pragma unroll
            for (int k = 0; k < 32; ++k) a = fmaf(xs[slot][k], w[k * 128 + j], a);
            out[(size_t)r * 128 + j] = fmaxf(a, 0.f);
        }
        __syncthreads();
    }
}

// ---- C[M,128] = act( [A1 | A2][M,K] @ W[K,128] + bias ), K in {128,256} ----
// A1 supplies k<128, A2 supplies k>=128 (both row-stride 128).
// Tile: 64 rows x 128 cols per block; thread (tx,ty) owns rows 8ty..8ty+7, cols 4tx..4tx+3.
__global__ __launch_bounds__(256) void sgemm_kernel(
    const float* __restrict__ A1, const float* __restrict__ A2,
    const float* __restrict__ W, const float* __restrict__ bias,
    float* __restrict__ C, int M, int K, int relu_flag)
{
    __shared__ float Xt[64 * 68];    // [k-chunk 64][row 64], stride 68
    __shared__ float Ws[64 * 128];   // [k-chunk 64][col 128]
    const int tid = threadIdx.x;
    const int tx = tid & 31;
    const int ty = tid >> 5;
    const int r0 = blockIdx.x * 64;

    float4 acc[8];
#pragma unroll
    for (int i = 0; i < 8; ++i) acc[i] = f4zero();

    for (int k0 = 0; k0 < K; k0 += 64) {
        const float* A = (k0 < 128) ? A1 : A2;
        const int kb = k0 & 127;
        __syncthreads();
        // stage A-chunk transposed: 64 rows x 64 k  (1024 float4 = 4 reps x 256)
#pragma unroll
        for (int rep = 0; rep < 4; ++rep) {
            const int fid = tid + rep * 256;
            const int row = fid >> 4, kq = fid & 15;
            float4 v = f4zero();
            const int r = r0 + row;
            if (r < M) v = *(const float4*)&A[(size_t)r * 128 + kb + 4 * kq];
            Xt[(4 * kq + 0) * 68 + row] = v.x;
            Xt[(4 * kq + 1) * 68 + row] = v.y;
            Xt[(4 * kq + 2) * 68 + row] = v.z;
            Xt[(4 * kq + 3) * 68 + row] = v.w;
        }
        // stage W-chunk: 64 rows x 128 cols (2048 float4 = 8 reps x 256)
#pragma unroll
        for (int rep = 0; rep < 8; ++rep) {
            const int fid = tid + rep * 256;
            const int row = fid >> 5, cq = fid & 31;
            *(float4*)&Ws[row * 128 + 4 * cq] =
                *(const float4*)&W[(size_t)(k0 + row) * 128 + 4 * cq];
        }
        __syncthreads();
#pragma unroll 4
        for (int kk = 0; kk < 64; ++kk) {
            const float4 w4 = *(const float4*)&Ws[kk * 128 + 4 * tx];
            const float4 xa = *(const float4*)&Xt[kk * 68 + 8 * ty];
            const float4 xb = *(const float4*)&Xt[kk * 68 + 8 * ty + 4];
            fma4(acc[0], xa.x, w4); fma4(acc[1], xa.y, w4);
            fma4(acc[2], xa.z, w4); fma4(acc[3], xa.w, w4);
            fma4(acc[4], xb.x, w4); fma4(acc[5], xb.y, w4);
            fma4(acc[6], xb.z, w4); fma4(acc[7], xb.w, w4);
        }
    }
    float4 b4 = f4zero();
    if (bias) b4 = *(const float4*)&bias[4 * tx];
#pragma unroll
    for (int i = 0; i < 8; ++i) {
        const int r = r0 + 8 * ty + i;
        if (r < M) {
            float4 v;
            v.x = acc[i].x + b4.x; v.y = acc[i].y + b4.y;
            v.z = acc[i].z + b4.z; v.w = acc[i].w + b4.w;
            if (relu_flag) {
                v.x = fmaxf(v.x, 0.f); v.y = fmaxf(v.y, 0.f);
                v.z = fmaxf(v.z, 0.f); v.w = fmaxf(v.w, 0.f);
            }
            *(float4*)&C[(size_t)r * 128 + 4 * tx] = v;
        }
    }
}

// ---- fused edge path: he = relu(ef@We+be); msg = relu(he@Wmid + bm + Psrc[src] + Pdst[dst]);
//      atomicAdd into agg[dst]. 64 edges x 128 cols per block. ----
__global__ __launch_bounds__(256) void edge_msg_gemm_kernel(
    const float* __restrict__ edge_feats, const int* __restrict__ ei,
    const float* __restrict__ We, const float* __restrict__ be,
    const float* __restrict__ Wmid, const float* __restrict__ bm,
    const float* __restrict__ Psrc, const float* __restrict__ Pdst,
    float* __restrict__ agg, int E)
{
    __shared__ float Xt[128 * 68];   // he transposed: [kmid 128][edge-row 64]
    __shared__ float Ws[32 * 128];   // Wmid chunk (32 rows: 1024 float4 = 4 reps)
    __shared__ float efs[64 * 17];   // edge feats, padded
    __shared__ float Wes[16 * 128];  // W_edge (512 float4 = 2 reps)
    const int tid = threadIdx.x;
    const int tx = tid & 31;
    const int ty = tid >> 5;
    const int e0 = blockIdx.x * 64;

    // stage edge feats (64 x 16): 256 float4 = 1 rep
    {
        const int row = tid >> 2, fq = tid & 3;
        float4 v = f4zero();
        if (e0 + row < E) v = *(const float4*)&edge_feats[(size_t)(e0 + row) * 16 + 4 * fq];
        efs[row * 17 + 4 * fq + 0] = v.x;
        efs[row * 17 + 4 * fq + 1] = v.y;
        efs[row * 17 + 4 * fq + 2] = v.z;
        efs[row * 17 + 4 * fq + 3] = v.w;
    }
    // stage We (16 x 128)
#pragma unroll
    for (int rep = 0; rep < 2; ++rep) {
        const int fid = tid + rep * 256;
        const int row = fid >> 5, cq = fid & 31;
        *(float4*)&Wes[row * 128 + 4 * cq] = *(const float4*)&We[(size_t)row * 128 + 4 * cq];
    }
    __syncthreads();

    // he phase: thread computes he for kmid=4tx+c, rows 8ty+i -> Xt
    float4 acc[8];
#pragma unroll
    for (int i = 0; i < 8; ++i) acc[i] = f4zero();
#pragma unroll
    for (int f = 0; f < 16; ++f) {
        const float4 w4 = *(const float4*)&Wes[f * 128 + 4 * tx];
#pragma unroll
        for (int i = 0; i < 8; ++i) {
            const float ev = efs[(8 * ty + i) * 17 + f];
            fma4(acc[i], ev, w4);
        }
    }
    {
        const float4 be4 = *(const float4*)&be[4 * tx];
#pragma unroll
        for (int i = 0; i < 8; ++i) {
            const int row = 8 * ty + i;
            Xt[(4 * tx + 0) * 68 + row] = fmaxf(acc[i].x + be4.x, 0.f);
            Xt[(4 * tx + 1) * 68 + row] = fmaxf(acc[i].y + be4.y, 0.f);
            Xt[(4 * tx + 2) * 68 + row] = fmaxf(acc[i].z + be4.z, 0.f);
            Xt[(4 * tx + 3) * 68 + row] = fmaxf(acc[i].w + be4.w, 0.f);
            acc[i] = f4zero();
        }
    }

    // main GEMM: msg_mid[row][col] = sum_k he[row][k] * Wmid[k][col], K=128 chunked by 32
    for (int k0 = 0; k0 < 128; k0 += 32) {
        __syncthreads();
#pragma unroll
        for (int rep = 0; rep < 4; ++rep) {
            const int fid = tid + rep * 256;
            const int row = fid >> 5, cq = fid & 31;
            *(float4*)&Ws[row * 128 + 4 * cq] =
                *(const float4*)&Wmid[(size_t)(k0 + row) * 128 + 4 * cq];
        }
        __syncthreads();
#pragma unroll 4
        for (int kk = 0; kk < 32; ++kk) {
            const float4 w4 = *(const float4*)&Ws[kk * 128 + 4 * tx];
            const float4 xa = *(const float4*)&Xt[(k0 + kk) * 68 + 8 * ty];
            const float4 xb = *(const float4*)&Xt[(k0 + kk) * 68 + 8 * ty + 4];
            fma4(acc[0], xa.x, w4); fma4(acc[1], xa.y, w4);
            fma4(acc[2], xa.z, w4); fma4(acc[3], xa.w, w4);
            fma4(acc[4], xb.x, w4); fma4(acc[5], xb.y, w4);
            fma4(acc[6], xb.z, w4); fma4(acc[7], xb.w, w4);
        }
    }

    // epilogue: + bm + Psrc[src] + Pdst[dst], relu, atomicAdd to agg[dst]
    const float4 bm4 = *(const float4*)&bm[4 * tx];
#pragma unroll
    for (int i = 0; i < 8; ++i) {
        const int e = e0 + 8 * ty + i;
        if (e < E) {
            const int s = ei[e];
            const int d = ei[E + e];
            const float4 ps = *(const float4*)&Psrc[(size_t)s * 128 + 4 * tx];
            const float4 pd = *(const float4*)&Pdst[(size_t)d * 128 + 4 * tx];
            float* ag = &agg[(size_t)d * 128 + 4 * tx];
            atomicAdd(ag + 0, fmaxf(acc[i].x + bm4.x + ps.x + pd.x, 0.f));
            atomicAdd(ag + 1, fmaxf(acc[i].y + bm4.y + ps.y + pd.y, 0.f));
            atomicAdd(ag + 2, fmaxf(acc[i].z + bm4.z + ps.z + pd.z, 0.f));
            atomicAdd(ag + 3, fmaxf(acc[i].w + bm4.w + ps.w + pd.w, 0.f));
        }
    }
}

// ---- readout: hid = relu(Qs[s]+Qd[t]+df@Wd+b1); out = sigmoid(hid.w2 + b2) ----
__global__ __launch_bounds__(256) void readout_kernel(
    const float* __restrict__ Qs, const float* __restrict__ Qd,
    const float* __restrict__ df, const int* __restrict__ dp,
    const float* __restrict__ Wd, const float* __restrict__ b1,
    const float* __restrict__ w2, const float* __restrict__ b2,
    float* __restrict__ out, int D)
{
    __shared__ float wd[8 * 128];
    __shared__ float partial[4];
    const int tid = threadIdx.x;
    const int j = tid & 127;
    const int slot = tid >> 7;
    for (int idx = tid; idx < 8 * 128; idx += 256) wd[idx] = Wd[idx];
    __syncthreads();
    const float bj = b1[j];
    const float w2j = w2[j];
    const float bb = b2[0];
    for (int d0 = blockIdx.x * 2; d0 < D; d0 += gridDim.x * 2) {
        const int d = d0 + slot;
        const bool valid = d < D;
        float v = 0.f;
        if (valid) {
            const int s = dp[2 * d], t = dp[2 * d + 1];
            float a = bj + Qs[(size_t)s * 128 + j] + Qd[(size_t)t * 128 + j];
#pragma unroll
            for (int k = 0; k < 8; ++k) a = fmaf(df[(size_t)d * 8 + k], wd[k * 128 + j], a);
            v = fmaxf(a, 0.f) * w2j;
        }
        for (int o = 32; o > 0; o >>= 1) v += __shfl_down(v, o);
        if ((tid & 63) == 0) partial[tid >> 6] = v;
        __syncthreads();
        if (valid && j == 0) {
            const float tot = partial[slot * 2] + partial[slot * 2 + 1] + bb;
            out[d] = 1.f / (1.f + __expf(-tot));
        }
        __syncthreads();
    }
}

extern "C" void kernel_launch(void* const* d_in, const int* in_sizes, int n_in,
                              void* d_out, int out_size, void* d_ws, size_t ws_size,
                              hipStream_t stream)
{
    const float* node_feats   = (const float*)d_in[0];
    const float* edge_feats   = (const float*)d_in[1];
    const float* demand_feats = (const float*)d_in[2];
    const int*   ei = (const int*)d_in[3];
    const int*   dp = (const int*)d_in[4];
    const float* W_node = (const float*)d_in[5];
    const float* b_node = (const float*)d_in[6];
    const float* W_edge = (const float*)d_in[7];
    const float* b_edge = (const float*)d_in[8];
    const float* Wm[2] = {(const float*)d_in[9],  (const float*)d_in[13]};
    const float* bm[2] = {(const float*)d_in[10], (const float*)d_in[14]};
    const float* Wu[2] = {(const float*)d_in[11], (const float*)d_in[15]};
    const float* bu[2] = {(const float*)d_in[12], (const float*)d_in[16]};
    const float* W_r1 = (const float*)d_in[17];
    const float* b_r1 = (const float*)d_in[18];
    const float* W_r2 = (const float*)d_in[19];
    const float* b_r2 = (const float*)d_in[20];
    float* out = (float*)d_out;

    const int NN = in_sizes[0] / 32;   // 20000
    const int NE = in_sizes[3] / 2;    // 640000
    const int ND = in_sizes[4] / 2;    // 100000

    // 4-buffer rotation (41 MB): Ps/Pd are dead once the edge kernel finishes,
    // so the update-GEMM output can reuse one of them.
    float* B0 = (float*)d_ws;
    float* B1 = B0 + (size_t)NN * 128;
    float* B2 = B1 + (size_t)NN * 128;
    float* B3 = B2 + (size_t)NN * 128;

    const int nbN = (NN + 63) / 64;   // node-GEMM blocks
    const int nbE = (NE + 63) / 64;   // edge blocks

    // encode -> B0
    encode_nodes_kernel<<<512, 256, 0, stream>>>(node_feats, W_node, b_node, B0, NN);

    // ---- layer 0: hin=B0 ----
    sgemm_kernel<<<nbN, 256, 0, stream>>>(B0, nullptr, Wm[0], nullptr, B1, NN, 128, 0);            // Ps=B1
    sgemm_kernel<<<nbN, 256, 0, stream>>>(B0, nullptr, Wm[0] + 256 * 128, nullptr, B2, NN, 128, 0); // Pd=B2
    hipMemsetAsync(B3, 0, (size_t)NN * 128 * sizeof(float), stream);                                // agg=B3
    edge_msg_gemm_kernel<<<nbE, 256, 0, stream>>>(edge_feats, ei, W_edge, b_edge,
                                                  Wm[0] + 128 * 128, bm[0], B1, B2, B3, NE);
    sgemm_kernel<<<nbN, 256, 0, stream>>>(B0, B3, Wu[0], bu[0], B1, NN, 256, 1);                    // hout=B1

    // ---- layer 1: hin=B1 ----
    sgemm_kernel<<<nbN, 256, 0, stream>>>(B1, nullptr, Wm[1], nullptr, B0, NN, 128, 0);            // Ps=B0
    sgemm_kernel<<<nbN, 256, 0, stream>>>(B1, nullptr, Wm[1] + 256 * 128, nullptr, B2, NN, 128, 0); // Pd=B2
    hipMemsetAsync(B3, 0, (size_t)NN * 128 * sizeof(float), stream);                                // agg=B3
    edge_msg_gemm_kernel<<<nbE, 256, 0, stream>>>(edge_feats, ei, W_edge, b_edge,
                                                  Wm[1] + 128 * 128, bm[1], B0, B2, B3, NE);
    sgemm_kernel<<<nbN, 256, 0, stream>>>(B1, B3, Wu[1], bu[1], B2, NN, 256, 1);                    // hfinal=B2

    // ---- readout ----
    sgemm_kernel<<<nbN, 256, 0, stream>>>(B2, nullptr, W_r1, nullptr, B0, NN, 128, 0);              // Qs=B0
    sgemm_kernel<<<nbN, 256, 0, stream>>>(B2, nullptr, W_r1 + 128 * 128, nullptr, B1, NN, 128, 0);  // Qd=B1
    readout_kernel<<<1024, 256, 0, stream>>>(B0, B1, demand_feats, dp,
                                             W_r1 + 256 * 128, b_r1, W_r2, b_r2, out, ND);
}

// Round 5
// 1245.962 us; speedup vs baseline: 2.0854x; 2.0854x over previous
//
#include <hip/hip_runtime.h>
#include <hip/hip_bf16.h>

__device__ __forceinline__ float4 f4zero() { return make_float4(0.f, 0.f, 0.f, 0.f); }

__device__ __forceinline__ void fma4(float4& a, float s, const float4& wv) {
    a.x = fmaf(s, wv.x, a.x);
    a.y = fmaf(s, wv.y, a.y);
    a.z = fmaf(s, wv.z, a.z);
    a.w = fmaf(s, wv.w, a.w);
}

// ---------------- sort pipeline: counting sort of edges by dst ----------------
__global__ __launch_bounds__(256) void hist_kernel(
    const int* __restrict__ ei, int* __restrict__ cnt, int E)
{
    const int i = blockIdx.x * blockDim.x + threadIdx.x;
    if (i < E) atomicAdd(&cnt[ei[E + i]], 1);
}

// single-block exclusive scan: fill[i] = sum_{k<i} cnt[k]
__global__ __launch_bounds__(256) void scan_kernel(
    const int* __restrict__ cnt, int* __restrict__ fill, int n)
{
    __shared__ int part[256];
    const int tid = threadIdx.x;
    const int chunk = (n + 255) / 256;
    const int beg = tid * chunk;
    const int end = min(beg + chunk, n);
    int s = 0;
    for (int i = beg; i < end; ++i) s += cnt[i];
    part[tid] = s;
    __syncthreads();
    for (int off = 1; off < 256; off <<= 1) {
        const int v = (tid >= off) ? part[tid - off] : 0;
        __syncthreads();
        part[tid] += v;
        __syncthreads();
    }
    int prefix = (tid == 0) ? 0 : part[tid - 1];
    for (int i = beg; i < end; ++i) { fill[i] = prefix; prefix += cnt[i]; }
}

__global__ __launch_bounds__(256) void scatter_kernel(
    const int* __restrict__ ei, int* __restrict__ fill,
    int* __restrict__ perm, int* __restrict__ ssrc, int* __restrict__ sdst, int E)
{
    const int e = blockIdx.x * blockDim.x + threadIdx.x;
    if (e < E) {
        const int d = ei[E + e];
        const int pos = atomicAdd(&fill[d], 1);
        perm[pos] = e;
        ssrc[pos] = ei[e];
        sdst[pos] = d;
    }
}

// ---------------- encode: h = relu(X[M,32] @ W[32,128] + b) ----------------
__global__ __launch_bounds__(256) void encode_nodes_kernel(
    const float* __restrict__ X, const float* __restrict__ W,
    const float* __restrict__ bias, float* __restrict__ out, int M)
{
    __shared__ float w[32 * 128];
    __shared__ float xs[2][32];
    const int tid = threadIdx.x;
    const int j = tid & 127;
    const int slot = tid >> 7;
    for (int idx = tid; idx < 32 * 128; idx += 256) w[idx] = W[idx];
    __syncthreads();
    const float bj = bias[j];
    for (int r0 = blockIdx.x * 2; r0 < M; r0 += gridDim.x * 2) {
        const int r = r0 + slot;
        const bool valid = r < M;
        if (valid && j < 32) xs[slot][j] = X[(size_t)r * 32 + j];
        __syncthreads();
        if (valid) {
            float a = bj;
#pragma unroll
            for (int k = 0; k < 32; ++k) a = fmaf(xs[slot][k], w[k * 128 + j], a);
            out[(size_t)r * 128 + j] = fmaxf(a, 0.f);
        }
        __syncthreads();
    }
}

// ---- C[M,128] = act( [A1 | A2][M,K] @ W[K,128] + bias ), K in {128,256} ----
__global__ __launch_bounds__(256) void sgemm_kernel(
    const float* __restrict__ A1, const float* __restrict__ A2,
    const float* __restrict__ W, const float* __restrict__ bias,
    float* __restrict__ C, int M, int K, int relu_flag)
{
    __shared__ float Xt[64 * 68];    // [k 64][row 64]
    __shared__ float Ws[64 * 128];   // [k 64][col 128]
    const int tid = threadIdx.x;
    const int tx = tid & 31;
    const int ty = tid >> 5;
    const int r0 = blockIdx.x * 64;

    float4 acc[8];
#pragma unroll
    for (int i = 0; i < 8; ++i) acc[i] = f4zero();

    for (int k0 = 0; k0 < K; k0 += 64) {
        const float* A = (k0 < 128) ? A1 : A2;
        const int kb = k0 & 127;
        __syncthreads();
#pragma unroll
        for (int rep = 0; rep < 4; ++rep) {
            const int fid = tid + rep * 256;
            const int row = fid >> 4, kq = fid & 15;
            float4 v = f4zero();
            const int r = r0 + row;
            if (r < M) v = *(const float4*)&A[(size_t)r * 128 + kb + 4 * kq];
            Xt[(4 * kq + 0) * 68 + row] = v.x;
            Xt[(4 * kq + 1) * 68 + row] = v.y;
            Xt[(4 * kq + 2) * 68 + row] = v.z;
            Xt[(4 * kq + 3) * 68 + row] = v.w;
        }
#pragma unroll
        for (int rep = 0; rep < 8; ++rep) {
            const int fid = tid + rep * 256;
            const int row = fid >> 5, cq = fid & 31;
            *(float4*)&Ws[row * 128 + 4 * cq] =
                *(const float4*)&W[(size_t)(k0 + row) * 128 + 4 * cq];
        }
        __syncthreads();
#pragma unroll 4
        for (int kk = 0; kk < 64; ++kk) {
            const float4 w4 = *(const float4*)&Ws[kk * 128 + 4 * tx];
            const float4 xa = *(const float4*)&Xt[kk * 68 + 8 * ty];
            const float4 xb = *(const float4*)&Xt[kk * 68 + 8 * ty + 4];
            fma4(acc[0], xa.x, w4); fma4(acc[1], xa.y, w4);
            fma4(acc[2], xa.z, w4); fma4(acc[3], xa.w, w4);
            fma4(acc[4], xb.x, w4); fma4(acc[5], xb.y, w4);
            fma4(acc[6], xb.z, w4); fma4(acc[7], xb.w, w4);
        }
    }
    float4 b4 = f4zero();
    if (bias) b4 = *(const float4*)&bias[4 * tx];
#pragma unroll
    for (int i = 0; i < 8; ++i) {
        const int r = r0 + 8 * ty + i;
        if (r < M) {
            float4 v;
            v.x = acc[i].x + b4.x; v.y = acc[i].y + b4.y;
            v.z = acc[i].z + b4.z; v.w = acc[i].w + b4.w;
            if (relu_flag) {
                v.x = fmaxf(v.x, 0.f); v.y = fmaxf(v.y, 0.f);
                v.z = fmaxf(v.z, 0.f); v.w = fmaxf(v.w, 0.f);
            }
            *(float4*)&C[(size_t)r * 128 + 4 * tx] = v;
        }
    }
}

// ---- fused edge path over dst-sorted edges + run-length segmented reduction ----
__global__ __launch_bounds__(256) void edge_msg_gemm_kernel(
    const float* __restrict__ edge_feats,
    const int* __restrict__ perm, const int* __restrict__ ssrc, const int* __restrict__ sdst,
    const float* __restrict__ We, const float* __restrict__ be,
    const float* __restrict__ Wmid, const float* __restrict__ bm,
    const float* __restrict__ Psrc, const float* __restrict__ Pdst,
    float* __restrict__ agg, int E)
{
    __shared__ float Xt[128 * 68];   // he^T [k 128][row 64]; later reused as ms[64][132]
    __shared__ float Ws[32 * 128];
    __shared__ float efs[64 * 17];
    __shared__ float Wes[16 * 128];
    __shared__ int sdh[64];
    __shared__ int ssh[64];
    const int tid = threadIdx.x;
    const int tx = tid & 31;
    const int ty = tid >> 5;
    const int p0 = blockIdx.x * 64;

    if (tid < 64) {
        const int p = p0 + tid;
        sdh[tid] = (p < E) ? sdst[p] : -1;
        ssh[tid] = (p < E) ? ssrc[p] : 0;
    }
    // stage edge feats (gather via perm)
    {
        const int row = tid >> 2, fq = tid & 3;
        const int p = p0 + row;
        float4 v = f4zero();
        if (p < E) {
            const int e = perm[p];
            v = *(const float4*)&edge_feats[(size_t)e * 16 + 4 * fq];
        }
        efs[row * 17 + 4 * fq + 0] = v.x;
        efs[row * 17 + 4 * fq + 1] = v.y;
        efs[row * 17 + 4 * fq + 2] = v.z;
        efs[row * 17 + 4 * fq + 3] = v.w;
    }
#pragma unroll
    for (int rep = 0; rep < 2; ++rep) {
        const int fid = tid + rep * 256;
        const int row = fid >> 5, cq = fid & 31;
        *(float4*)&Wes[row * 128 + 4 * cq] = *(const float4*)&We[(size_t)row * 128 + 4 * cq];
    }
    __syncthreads();

    // he = relu(ef @ We + be), written transposed into Xt
    float4 acc[8];
#pragma unroll
    for (int i = 0; i < 8; ++i) acc[i] = f4zero();
#pragma unroll
    for (int f = 0; f < 16; ++f) {
        const float4 w4 = *(const float4*)&Wes[f * 128 + 4 * tx];
#pragma unroll
        for (int i = 0; i < 8; ++i) fma4(acc[i], efs[(8 * ty + i) * 17 + f], w4);
    }
    {
        const float4 be4 = *(const float4*)&be[4 * tx];
#pragma unroll
        for (int i = 0; i < 8; ++i) {
            const int row = 8 * ty + i;
            Xt[(4 * tx + 0) * 68 + row] = fmaxf(acc[i].x + be4.x, 0.f);
            Xt[(4 * tx + 1) * 68 + row] = fmaxf(acc[i].y + be4.y, 0.f);
            Xt[(4 * tx + 2) * 68 + row] = fmaxf(acc[i].z + be4.z, 0.f);
            Xt[(4 * tx + 3) * 68 + row] = fmaxf(acc[i].w + be4.w, 0.f);
            acc[i] = f4zero();
        }
    }

    // mid GEMM: K=128 in chunks of 32
    for (int k0 = 0; k0 < 128; k0 += 32) {
        __syncthreads();
#pragma unroll
        for (int rep = 0; rep < 4; ++rep) {
            const int fid = tid + rep * 256;
            const int row = fid >> 5, cq = fid & 31;
            *(float4*)&Ws[row * 128 + 4 * cq] =
                *(const float4*)&Wmid[(size_t)(k0 + row) * 128 + 4 * cq];
        }
        __syncthreads();
#pragma unroll 4
        for (int kk = 0; kk < 32; ++kk) {
            const float4 w4 = *(const float4*)&Ws[kk * 128 + 4 * tx];
            const float4 xa = *(const float4*)&Xt[(k0 + kk) * 68 + 8 * ty];
            const float4 xb = *(const float4*)&Xt[(k0 + kk) * 68 + 8 * ty + 4];
            fma4(acc[0], xa.x, w4); fma4(acc[1], xa.y, w4);
            fma4(acc[2], xa.z, w4); fma4(acc[3], xa.w, w4);
            fma4(acc[4], xb.x, w4); fma4(acc[5], xb.y, w4);
            fma4(acc[6], xb.z, w4); fma4(acc[7], xb.w, w4);
        }
    }

    __syncthreads();                 // Xt reads done; safe to reuse as ms
    float* ms = Xt;                  // ms[row][col], stride 132 (64*132 <= 128*68)

    const float4 bm4 = *(const float4*)&bm[4 * tx];
#pragma unroll
    for (int i = 0; i < 8; ++i) {
        const int row = 8 * ty + i;
        const int p = p0 + row;
        if (p < E) {
            const int s = ssh[row];
            const int d = sdh[row];
            const float4 ps = *(const float4*)&Psrc[(size_t)s * 128 + 4 * tx];
            const float4 pd = *(const float4*)&Pdst[(size_t)d * 128 + 4 * tx];
            float4 v;
            v.x = fmaxf(acc[i].x + bm4.x + ps.x + pd.x, 0.f);
            v.y = fmaxf(acc[i].y + bm4.y + ps.y + pd.y, 0.f);
            v.z = fmaxf(acc[i].z + bm4.z + ps.z + pd.z, 0.f);
            v.w = fmaxf(acc[i].w + bm4.w + ps.w + pd.w, 0.f);
            *(float4*)&ms[row * 132 + 4 * tx] = v;
        }
    }
    __syncthreads();

    // segmented reduction: thread scans 32 rows of one column, one atomic per dst-run
    {
        const int j = tid & 127;
        const int base = (tid < 128) ? 0 : 32;
        float a = 0.f;
        for (int r = base; r < base + 32; ++r) {
            const int d = sdh[r];
            if (d < 0) break;
            a += ms[r * 132 + j];
            if (r == base + 31 || sdh[r + 1] != d) {
                atomicAdd(&agg[(size_t)d * 128 + j], a);
                a = 0.f;
            }
        }
    }
}

// ---- readout ----
__global__ __launch_bounds__(256) void readout_kernel(
    const float* __restrict__ Qs, const float* __restrict__ Qd,
    const float* __restrict__ df, const int* __restrict__ dp,
    const float* __restrict__ Wd, const float* __restrict__ b1,
    const float* __restrict__ w2, const float* __restrict__ b2,
    float* __restrict__ out, int D)
{
    __shared__ float wd[8 * 128];
    __shared__ float partial[4];
    const int tid = threadIdx.x;
    const int j = tid & 127;
    const int slot = tid >> 7;
    for (int idx = tid; idx < 8 * 128; idx += 256) wd[idx] = Wd[idx];
    __syncthreads();
    const float bj = b1[j];
    const float w2j = w2[j];
    const float bb = b2[0];
    for (int d0 = blockIdx.x * 2; d0 < D; d0 += gridDim.x * 2) {
        const int d = d0 + slot;
        const bool valid = d < D;
        float v = 0.f;
        if (valid) {
            const int s = dp[2 * d], t = dp[2 * d + 1];
            float a = bj + Qs[(size_t)s * 128 + j] + Qd[(size_t)t * 128 + j];
#pragma unroll
            for (int k = 0; k < 8; ++k) a = fmaf(df[(size_t)d * 8 + k], wd[k * 128 + j], a);
            v = fmaxf(a, 0.f) * w2j;
        }
        for (int o = 32; o > 0; o >>= 1) v += __shfl_down(v, o);
        if ((tid & 63) == 0) partial[tid >> 6] = v;
        __syncthreads();
        if (valid && j == 0) {
            const float tot = partial[slot * 2] + partial[slot * 2 + 1] + bb;
            out[d] = 1.f / (1.f + __expf(-tot));
        }
        __syncthreads();
    }
}

extern "C" void kernel_launch(void* const* d_in, const int* in_sizes, int n_in,
                              void* d_out, int out_size, void* d_ws, size_t ws_size,
                              hipStream_t stream)
{
    const float* node_feats   = (const float*)d_in[0];
    const float* edge_feats   = (const float*)d_in[1];
    const float* demand_feats = (const float*)d_in[2];
    const int*   ei = (const int*)d_in[3];
    const int*   dp = (const int*)d_in[4];
    const float* W_node = (const float*)d_in[5];
    const float* b_node = (const float*)d_in[6];
    const float* W_edge = (const float*)d_in[7];
    const float* b_edge = (const float*)d_in[8];
    const float* Wm[2] = {(const float*)d_in[9],  (const float*)d_in[13]};
    const float* bm[2] = {(const float*)d_in[10], (const float*)d_in[14]};
    const float* Wu[2] = {(const float*)d_in[11], (const float*)d_in[15]};
    const float* bu[2] = {(const float*)d_in[12], (const float*)d_in[16]};
    const float* W_r1 = (const float*)d_in[17];
    const float* b_r1 = (const float*)d_in[18];
    const float* W_r2 = (const float*)d_in[19];
    const float* b_r2 = (const float*)d_in[20];
    float* out = (float*)d_out;

    const int NN = in_sizes[0] / 32;   // 20000
    const int NE = in_sizes[3] / 2;    // 640000
    const int ND = in_sizes[4] / 2;    // 100000

    // workspace layout (~48.8 MB)
    float* B0 = (float*)d_ws;
    float* B1 = B0 + (size_t)NN * 128;
    float* B2 = B1 + (size_t)NN * 128;
    float* B3 = B2 + (size_t)NN * 128;
    int* cnt  = (int*)(B3 + (size_t)NN * 128);
    int* fill = cnt + NN;
    int* perm = fill + NN;
    int* ssrc = perm + NE;
    int* sdst = ssrc + NE;

    const int nbN = (NN + 63) / 64;
    const int nbE = (NE + 63) / 64;

    // ---- sort edges by dst (once per launch) ----
    hipMemsetAsync(cnt, 0, NN * sizeof(int), stream);
    hist_kernel<<<(NE + 255) / 256, 256, 0, stream>>>(ei, cnt, NE);
    scan_kernel<<<1, 256, 0, stream>>>(cnt, fill, NN);
    scatter_kernel<<<(NE + 255) / 256, 256, 0, stream>>>(ei, fill, perm, ssrc, sdst, NE);

    // encode -> B0
    encode_nodes_kernel<<<512, 256, 0, stream>>>(node_feats, W_node, b_node, B0, NN);

    // ---- layer 0: hin=B0 ----
    sgemm_kernel<<<nbN, 256, 0, stream>>>(B0, nullptr, Wm[0], nullptr, B1, NN, 128, 0);             // Ps=B1
    sgemm_kernel<<<nbN, 256, 0, stream>>>(B0, nullptr, Wm[0] + 256 * 128, nullptr, B2, NN, 128, 0); // Pd=B2
    hipMemsetAsync(B3, 0, (size_t)NN * 128 * sizeof(float), stream);                                // agg=B3
    edge_msg_gemm_kernel<<<nbE, 256, 0, stream>>>(edge_feats, perm, ssrc, sdst, W_edge, b_edge,
                                                  Wm[0] + 128 * 128, bm[0], B1, B2, B3, NE);
    sgemm_kernel<<<nbN, 256, 0, stream>>>(B0, B3, Wu[0], bu[0], B1, NN, 256, 1);                    // hout=B1

    // ---- layer 1: hin=B1 ----
    sgemm_kernel<<<nbN, 256, 0, stream>>>(B1, nullptr, Wm[1], nullptr, B0, NN, 128, 0);             // Ps=B0
    sgemm_kernel<<<nbN, 256, 0, stream>>>(B1, nullptr, Wm[1] + 256 * 128, nullptr, B2, NN, 128, 0); // Pd=B2
    hipMemsetAsync(B3, 0, (size_t)NN * 128 * sizeof(float), stream);                                // agg=B3
    edge_msg_gemm_kernel<<<nbE, 256, 0, stream>>>(edge_feats, perm, ssrc, sdst, W_edge, b_edge,
                                                  Wm[1] + 128 * 128, bm[1], B0, B2, B3, NE);
    sgemm_kernel<<<nbN, 256, 0, stream>>>(B1, B3, Wu[1], bu[1], B2, NN, 256, 1);                    // hfinal=B2

    // ---- readout ----
    sgemm_kernel<<<nbN, 256, 0, stream>>>(B2, nullptr, W_r1, nullptr, B0, NN, 128, 0);              // Qs=B0
    sgemm_kernel<<<nbN, 256, 0, stream>>>(B2, nullptr, W_r1 + 128 * 128, nullptr, B1, NN, 128, 0);  // Qd=B1
    readout_kernel<<<1024, 256, 0, stream>>>(B0, B1, demand_feats, dp,
                                             W_r1 + 256 * 128, b_r1, W_r2, b_r2, out, ND);
}

// Round 6
// 1041.020 us; speedup vs baseline: 2.4960x; 1.1969x over previous
//
#include <hip/hip_runtime.h>
#include <hip/hip_bf16.h>

using short8  = __attribute__((ext_vector_type(8))) short;
using short4v = __attribute__((ext_vector_type(4))) short;
using float4v = __attribute__((ext_vector_type(4))) float;

__device__ __forceinline__ float4 f4zero() { return make_float4(0.f, 0.f, 0.f, 0.f); }

__device__ __forceinline__ void fma4(float4& a, float s, const float4& wv) {
    a.x = fmaf(s, wv.x, a.x);
    a.y = fmaf(s, wv.y, a.y);
    a.z = fmaf(s, wv.z, a.z);
    a.w = fmaf(s, wv.w, a.w);
}

__device__ __forceinline__ float bfhi2f(unsigned short u) {
    return __uint_as_float(((unsigned int)u) << 16);
}
// round-to-nearest-even fp32 -> bf16
__device__ __forceinline__ unsigned short f2bf_rn(float x) {
    unsigned int u = __float_as_uint(x);
    u += 0x7FFFu + ((u >> 16) & 1u);
    return (unsigned short)(u >> 16);
}
__device__ __forceinline__ void split_bf(float v, unsigned short& h, unsigned short& l) {
    h = f2bf_rn(v);
    l = f2bf_rn(v - bfhi2f(h));
}
__device__ __forceinline__ short8 ld_s8(const unsigned short* p) {   // 16B-aligned
    return *(const short8*)p;
}
__device__ __forceinline__ short8 ld_s8_2x64(const unsigned short* p) { // 8B-aligned
    short4v a = *(const short4v*)p;
    short4v b = *(const short4v*)(p + 4);
    short8 r = {a[0], a[1], a[2], a[3], b[0], b[1], b[2], b[3]};
    return r;
}

// ---------------- sort pipeline: counting sort of edges by dst ----------------
__global__ __launch_bounds__(256) void hist_kernel(
    const int* __restrict__ ei, int* __restrict__ cnt, int E)
{
    const int i = blockIdx.x * blockDim.x + threadIdx.x;
    if (i < E) atomicAdd(&cnt[ei[E + i]], 1);
}

__global__ __launch_bounds__(256) void scan_kernel(
    const int* __restrict__ cnt, int* __restrict__ fill, int n)
{
    __shared__ int part[256];
    const int tid = threadIdx.x;
    const int chunk = (n + 255) / 256;
    const int beg = tid * chunk;
    const int end = min(beg + chunk, n);
    int s = 0;
    for (int i = beg; i < end; ++i) s += cnt[i];
    part[tid] = s;
    __syncthreads();
    for (int off = 1; off < 256; off <<= 1) {
        const int v = (tid >= off) ? part[tid - off] : 0;
        __syncthreads();
        part[tid] += v;
        __syncthreads();
    }
    int prefix = (tid == 0) ? 0 : part[tid - 1];
    for (int i = beg; i < end; ++i) { fill[i] = prefix; prefix += cnt[i]; }
}

__global__ __launch_bounds__(256) void scatter_kernel(
    const int* __restrict__ ei, int* __restrict__ fill,
    int* __restrict__ perm, int* __restrict__ ssrc, int* __restrict__ sdst, int E)
{
    const int e = blockIdx.x * blockDim.x + threadIdx.x;
    if (e < E) {
        const int d = ei[E + e];
        const int pos = atomicAdd(&fill[d], 1);
        perm[pos] = e;
        ssrc[pos] = ei[e];
        sdst[pos] = d;
    }
}

// ---------------- encode: h = relu(X[M,32] @ W[32,128] + b) ----------------
__global__ __launch_bounds__(256) void encode_nodes_kernel(
    const float* __restrict__ X, const float* __restrict__ W,
    const float* __restrict__ bias, float* __restrict__ out, int M)
{
    __shared__ float w[32 * 128];
    __shared__ float xs[2][32];
    const int tid = threadIdx.x;
    const int j = tid & 127;
    const int slot = tid >> 7;
    for (int idx = tid; idx < 32 * 128; idx += 256) w[idx] = W[idx];
    __syncthreads();
    const float bj = bias[j];
    for (int r0 = blockIdx.x * 2; r0 < M; r0 += gridDim.x * 2) {
        const int r = r0 + slot;
        const bool valid = r < M;
        if (valid && j < 32) xs[slot][j] = X[(size_t)r * 32 + j];
        __syncthreads();
        if (valid) {
            float a = bj;
#pragma unroll
            for (int k = 0; k < 32; ++k) a = fmaf(xs[slot][k], w[k * 128 + j], a);
            out[(size_t)r * 128 + j] = fmaxf(a, 0.f);
        }
        __syncthreads();
    }
}

// ---- C[M,128] = act( [A1 | A2][M,K] @ W[K,128] + bias ), K in {128,256} ----
__global__ __launch_bounds__(256) void sgemm_kernel(
    const float* __restrict__ A1, const float* __restrict__ A2,
    const float* __restrict__ W, const float* __restrict__ bias,
    float* __restrict__ C, int M, int K, int relu_flag)
{
    __shared__ float Xt[64 * 68];
    __shared__ float Ws[64 * 128];
    const int tid = threadIdx.x;
    const int tx = tid & 31;
    const int ty = tid >> 5;
    const int r0 = blockIdx.x * 64;

    float4 acc[8];
#pragma unroll
    for (int i = 0; i < 8; ++i) acc[i] = f4zero();

    for (int k0 = 0; k0 < K; k0 += 64) {
        const float* A = (k0 < 128) ? A1 : A2;
        const int kb = k0 & 127;
        __syncthreads();
#pragma unroll
        for (int rep = 0; rep < 4; ++rep) {
            const int fid = tid + rep * 256;
            const int row = fid >> 4, kq = fid & 15;
            float4 v = f4zero();
            const int r = r0 + row;
            if (r < M) v = *(const float4*)&A[(size_t)r * 128 + kb + 4 * kq];
            Xt[(4 * kq + 0) * 68 + row] = v.x;
            Xt[(4 * kq + 1) * 68 + row] = v.y;
            Xt[(4 * kq + 2) * 68 + row] = v.z;
            Xt[(4 * kq + 3) * 68 + row] = v.w;
        }
#pragma unroll
        for (int rep = 0; rep < 8; ++rep) {
            const int fid = tid + rep * 256;
            const int row = fid >> 5, cq = fid & 31;
            *(float4*)&Ws[row * 128 + 4 * cq] =
                *(const float4*)&W[(size_t)(k0 + row) * 128 + 4 * cq];
        }
        __syncthreads();
#pragma unroll 4
        for (int kk = 0; kk < 64; ++kk) {
            const float4 w4 = *(const float4*)&Ws[kk * 128 + 4 * tx];
            const float4 xa = *(const float4*)&Xt[kk * 68 + 8 * ty];
            const float4 xb = *(const float4*)&Xt[kk * 68 + 8 * ty + 4];
            fma4(acc[0], xa.x, w4); fma4(acc[1], xa.y, w4);
            fma4(acc[2], xa.z, w4); fma4(acc[3], xa.w, w4);
            fma4(acc[4], xb.x, w4); fma4(acc[5], xb.y, w4);
            fma4(acc[6], xb.z, w4); fma4(acc[7], xb.w, w4);
        }
    }
    float4 b4 = f4zero();
    if (bias) b4 = *(const float4*)&bias[4 * tx];
#pragma unroll
    for (int i = 0; i < 8; ++i) {
        const int r = r0 + 8 * ty + i;
        if (r < M) {
            float4 v;
            v.x = acc[i].x + b4.x; v.y = acc[i].y + b4.y;
            v.z = acc[i].z + b4.z; v.w = acc[i].w + b4.w;
            if (relu_flag) {
                v.x = fmaxf(v.x, 0.f); v.y = fmaxf(v.y, 0.f);
                v.z = fmaxf(v.z, 0.f); v.w = fmaxf(v.w, 0.f);
            }
            *(float4*)&C[(size_t)r * 128 + 4 * tx] = v;
        }
    }
}

// ---- fused edge path, split-bf16 MFMA version ----
// Per block: 64 dst-sorted edges x 128 cols.
//   he = relu(ef @ We + be)          via 16x16x32 MFMA, K=16 zero-padded
//   mid = he @ Wmid                  via 16x16x32 MFMA, K=128 in 4 chunks
//   msg = relu(mid + bm + Ps[src] + Pd[dst]); run-length-reduced atomicAdd into agg.
// All matmuls use x = hi + lo bf16 split: 3 MFMAs (hh, hl, lh) per tile.
__global__ __launch_bounds__(256) void edge_msg_mfma_kernel(
    const float* __restrict__ edge_feats,
    const int* __restrict__ perm, const int* __restrict__ ssrc, const int* __restrict__ sdst,
    const float* __restrict__ We, const float* __restrict__ be,
    const float* __restrict__ Wmid, const float* __restrict__ bm,
    const float* __restrict__ Psrc, const float* __restrict__ Pdst,
    float* __restrict__ agg, int E)
{
    // LDS layout (bytes):
    //      0: ahi [64][136] u16 (17408)   he hi, row-major, padded stride
    //  17408: alo [64][136] u16 (17408)
    //  34816: wth [128][36] u16 ( 9216)   Wmid chunk, transposed [n][k], per-chunk
    //  44032: wtl [128][36] u16 ( 9216)
    //  he-phase overlay of wth/wtl region:
    //  34816: efh [64][24] u16 (3072) | 37888: efl (3072)
    //  40960: weh [128][24] u16 (6144) | 47104: wel (6144)   (ends 53248)
    //  53248: sdh[64] int | 53504: ssh[64] int  -> 53760 total
    //  ms [64][132] f32 (33792) overlays 0..33792 after MFMA phases.
    __shared__ __align__(16) char smem[53760];
    unsigned short* ahi = (unsigned short*)smem;
    unsigned short* alo = (unsigned short*)(smem + 17408);
    unsigned short* wth = (unsigned short*)(smem + 34816);
    unsigned short* wtl = (unsigned short*)(smem + 44032);
    unsigned short* efh = (unsigned short*)(smem + 34816);
    unsigned short* efl = (unsigned short*)(smem + 37888);
    unsigned short* weh = (unsigned short*)(smem + 40960);
    unsigned short* wel = (unsigned short*)(smem + 47104);
    float* ms = (float*)smem;
    int* sdh = (int*)(smem + 53248);
    int* ssh = (int*)(smem + 53504);

    const int tid = threadIdx.x;
    const int w = tid >> 6;          // wave 0..3
    const int l = tid & 63;
    const int quad = l >> 4;
    const int l16 = l & 15;
    const int p0 = blockIdx.x * 64;

    if (tid < 64) {
        const int p = p0 + tid;
        sdh[tid] = (p < E) ? sdst[p] : -1;
        ssh[tid] = (p < E) ? ssrc[p] : 0;
    }
    // stage edge feats (gather via perm), split to bf16 hi/lo
    {
        const int row = tid >> 2, c4 = (tid & 3) * 4;
        const int p = p0 + row;
        float4 v = f4zero();
        if (p < E) {
            const int e = perm[p];
            v = *(const float4*)&edge_feats[(size_t)e * 16 + c4];
        }
        unsigned short h, lo;
        split_bf(v.x, h, lo); efh[row * 24 + c4 + 0] = h; efl[row * 24 + c4 + 0] = lo;
        split_bf(v.y, h, lo); efh[row * 24 + c4 + 1] = h; efl[row * 24 + c4 + 1] = lo;
        split_bf(v.z, h, lo); efh[row * 24 + c4 + 2] = h; efl[row * 24 + c4 + 2] = lo;
        split_bf(v.w, h, lo); efh[row * 24 + c4 + 3] = h; efl[row * 24 + c4 + 3] = lo;
    }
    // stage We transposed [n][k], split hi/lo (16x128 = 512 float4)
#pragma unroll
    for (int rep = 0; rep < 2; ++rep) {
        const int idx = rep * 256 + tid;
        const int k = idx >> 5, nq = idx & 31;
        const float4 v = *(const float4*)&We[(size_t)k * 128 + 4 * nq];
        unsigned short h, lo;
        split_bf(v.x, h, lo); weh[(4 * nq + 0) * 24 + k] = h; wel[(4 * nq + 0) * 24 + k] = lo;
        split_bf(v.y, h, lo); weh[(4 * nq + 1) * 24 + k] = h; wel[(4 * nq + 1) * 24 + k] = lo;
        split_bf(v.z, h, lo); weh[(4 * nq + 2) * 24 + k] = h; wel[(4 * nq + 2) * 24 + k] = lo;
        split_bf(v.w, h, lo); weh[(4 * nq + 3) * 24 + k] = h; wel[(4 * nq + 3) * 24 + k] = lo;
    }
    __syncthreads();

    const short8 zf = {0, 0, 0, 0, 0, 0, 0, 0};
    float4v acc[4][2];

    // ---- he phase: MFMA over K=16 (quads 2,3 contribute zeros) ----
#pragma unroll
    for (int mt = 0; mt < 4; ++mt)
#pragma unroll
        for (int t = 0; t < 2; ++t) acc[mt][t] = (float4v)0.f;

    {
        short8 bh[2], bl[2];
#pragma unroll
        for (int t = 0; t < 2; ++t) {
            const int nt = 2 * w + t;
            if (quad < 2) {
                const int base = (nt * 16 + l16) * 24 + quad * 8;
                bh[t] = ld_s8(&weh[base]);
                bl[t] = ld_s8(&wel[base]);
            } else { bh[t] = zf; bl[t] = zf; }
        }
#pragma unroll
        for (int mt = 0; mt < 4; ++mt) {
            short8 ah = zf, al = zf;
            if (quad < 2) {
                const int base = (mt * 16 + l16) * 24 + quad * 8;
                ah = ld_s8(&efh[base]);
                al = ld_s8(&efl[base]);
            }
#pragma unroll
            for (int t = 0; t < 2; ++t) {
                acc[mt][t] = __builtin_amdgcn_mfma_f32_16x16x32_bf16(ah, bh[t], acc[mt][t], 0, 0, 0);
                acc[mt][t] = __builtin_amdgcn_mfma_f32_16x16x32_bf16(ah, bl[t], acc[mt][t], 0, 0, 0);
                acc[mt][t] = __builtin_amdgcn_mfma_f32_16x16x32_bf16(al, bh[t], acc[mt][t], 0, 0, 0);
            }
        }
        // bias + relu + split -> ahi/alo (A operand of mid GEMM)
#pragma unroll
        for (int t = 0; t < 2; ++t) {
            const int col = (2 * w + t) * 16 + l16;
            const float bcol = be[col];
#pragma unroll
            for (int mt = 0; mt < 4; ++mt)
#pragma unroll
                for (int r = 0; r < 4; ++r) {
                    const int row = mt * 16 + quad * 4 + r;
                    const float v = fmaxf(acc[mt][t][r] + bcol, 0.f);
                    unsigned short h, lo;
                    split_bf(v, h, lo);
                    ahi[row * 136 + col] = h;
                    alo[row * 136 + col] = lo;
                }
        }
    }
    __syncthreads();

    // ---- mid GEMM: K=128 in 4 chunks of 32 ----
#pragma unroll
    for (int mt = 0; mt < 4; ++mt)
#pragma unroll
        for (int t = 0; t < 2; ++t) acc[mt][t] = (float4v)0.f;

    for (int c = 0; c < 4; ++c) {
        const int k0 = c * 32;
        // stage Wmid chunk transposed+split (32x128 = 1024 float4)
#pragma unroll
        for (int rep = 0; rep < 4; ++rep) {
            const int idx = rep * 256 + tid;
            const int kk = idx >> 5, nq = idx & 31;
            const float4 v = *(const float4*)&Wmid[(size_t)(k0 + kk) * 128 + 4 * nq];
            unsigned short h, lo;
            split_bf(v.x, h, lo); wth[(4 * nq + 0) * 36 + kk] = h; wtl[(4 * nq + 0) * 36 + kk] = lo;
            split_bf(v.y, h, lo); wth[(4 * nq + 1) * 36 + kk] = h; wtl[(4 * nq + 1) * 36 + kk] = lo;
            split_bf(v.z, h, lo); wth[(4 * nq + 2) * 36 + kk] = h; wtl[(4 * nq + 2) * 36 + kk] = lo;
            split_bf(v.w, h, lo); wth[(4 * nq + 3) * 36 + kk] = h; wtl[(4 * nq + 3) * 36 + kk] = lo;
        }
        __syncthreads();
        short8 bh[2], bl[2];
#pragma unroll
        for (int t = 0; t < 2; ++t) {
            const int base = ((2 * w + t) * 16 + l16) * 36 + quad * 8;
            bh[t] = ld_s8_2x64(&wth[base]);
            bl[t] = ld_s8_2x64(&wtl[base]);
        }
#pragma unroll
        for (int mt = 0; mt < 4; ++mt) {
            const int base = (mt * 16 + l16) * 136 + k0 + quad * 8;
            const short8 ah = ld_s8(&ahi[base]);
            const short8 al = ld_s8(&alo[base]);
#pragma unroll
            for (int t = 0; t < 2; ++t) {
                acc[mt][t] = __builtin_amdgcn_mfma_f32_16x16x32_bf16(ah, bh[t], acc[mt][t], 0, 0, 0);
                acc[mt][t] = __builtin_amdgcn_mfma_f32_16x16x32_bf16(ah, bl[t], acc[mt][t], 0, 0, 0);
                acc[mt][t] = __builtin_amdgcn_mfma_f32_16x16x32_bf16(al, bh[t], acc[mt][t], 0, 0, 0);
            }
        }
        __syncthreads();   // wth reads done before restage / ms overlay
    }

    // ---- spill mid to ms[64][132] (C layout -> row-major) ----
#pragma unroll
    for (int mt = 0; mt < 4; ++mt)
#pragma unroll
        for (int t = 0; t < 2; ++t) {
            const int col = (2 * w + t) * 16 + l16;
#pragma unroll
            for (int r = 0; r < 4; ++r)
                ms[(mt * 16 + quad * 4 + r) * 132 + col] = acc[mt][t][r];
        }
    __syncthreads();

    // ---- epilogue: + bm + Ps[src] + Pd[dst], relu, back into ms ----
    {
        const int tx = tid & 31, ty = tid >> 5;
        const float4 bm4 = *(const float4*)&bm[4 * tx];
#pragma unroll
        for (int i = 0; i < 8; ++i) {
            const int row = 8 * ty + i;
            const int p = p0 + row;
            if (p < E) {
                const int s = ssh[row];
                const int d = sdh[row];
                const float4 ps = *(const float4*)&Psrc[(size_t)s * 128 + 4 * tx];
                const float4 pd = *(const float4*)&Pdst[(size_t)d * 128 + 4 * tx];
                float4 m4 = *(const float4*)&ms[row * 132 + 4 * tx];
                m4.x = fmaxf(m4.x + bm4.x + ps.x + pd.x, 0.f);
                m4.y = fmaxf(m4.y + bm4.y + ps.y + pd.y, 0.f);
                m4.z = fmaxf(m4.z + bm4.z + ps.z + pd.z, 0.f);
                m4.w = fmaxf(m4.w + bm4.w + ps.w + pd.w, 0.f);
                *(float4*)&ms[row * 132 + 4 * tx] = m4;
            }
        }
    }
    __syncthreads();

    // ---- run-length segmented reduction: one atomic per dst-run per column ----
    {
        const int j = tid & 127;
        const int base = (tid < 128) ? 0 : 32;
        float a = 0.f;
        for (int r = base; r < base + 32; ++r) {
            const int d = sdh[r];
            if (d < 0) break;
            a += ms[r * 132 + j];
            if (r == base + 31 || sdh[r + 1] != d) {
                atomicAdd(&agg[(size_t)d * 128 + j], a);
                a = 0.f;
            }
        }
    }
}

// ---- readout ----
__global__ __launch_bounds__(256) void readout_kernel(
    const float* __restrict__ Qs, const float* __restrict__ Qd,
    const float* __restrict__ df, const int* __restrict__ dp,
    const float* __restrict__ Wd, const float* __restrict__ b1,
    const float* __restrict__ w2, const float* __restrict__ b2,
    float* __restrict__ out, int D)
{
    __shared__ float wd[8 * 128];
    __shared__ float partial[4];
    const int tid = threadIdx.x;
    const int j = tid & 127;
    const int slot = tid >> 7;
    for (int idx = tid; idx < 8 * 128; idx += 256) wd[idx] = Wd[idx];
    __syncthreads();
    const float bj = b1[j];
    const float w2j = w2[j];
    const float bb = b2[0];
    for (int d0 = blockIdx.x * 2; d0 < D; d0 += gridDim.x * 2) {
        const int d = d0 + slot;
        const bool valid = d < D;
        float v = 0.f;
        if (valid) {
            const int s = dp[2 * d], t = dp[2 * d + 1];
            float a = bj + Qs[(size_t)s * 128 + j] + Qd[(size_t)t * 128 + j];
#pragma unroll
            for (int k = 0; k < 8; ++k) a = fmaf(df[(size_t)d * 8 + k], wd[k * 128 + j], a);
            v = fmaxf(a, 0.f) * w2j;
        }
        for (int o = 32; o > 0; o >>= 1) v += __shfl_down(v, o);
        if ((tid & 63) == 0) partial[tid >> 6] = v;
        __syncthreads();
        if (valid && j == 0) {
            const float tot = partial[slot * 2] + partial[slot * 2 + 1] + bb;
            out[d] = 1.f / (1.f + __expf(-tot));
        }
        __syncthreads();
    }
}

extern "C" void kernel_launch(void* const* d_in, const int* in_sizes, int n_in,
                              void* d_out, int out_size, void* d_ws, size_t ws_size,
                              hipStream_t stream)
{
    const float* node_feats   = (const float*)d_in[0];
    const float* edge_feats   = (const float*)d_in[1];
    const float* demand_feats = (const float*)d_in[2];
    const int*   ei = (const int*)d_in[3];
    const int*   dp = (const int*)d_in[4];
    const float* W_node = (const float*)d_in[5];
    const float* b_node = (const float*)d_in[6];
    const float* W_edge = (const float*)d_in[7];
    const float* b_edge = (const float*)d_in[8];
    const float* Wm[2] = {(const float*)d_in[9],  (const float*)d_in[13]};
    const float* bm[2] = {(const float*)d_in[10], (const float*)d_in[14]};
    const float* Wu[2] = {(const float*)d_in[11], (const float*)d_in[15]};
    const float* bu[2] = {(const float*)d_in[12], (const float*)d_in[16]};
    const float* W_r1 = (const float*)d_in[17];
    const float* b_r1 = (const float*)d_in[18];
    const float* W_r2 = (const float*)d_in[19];
    const float* b_r2 = (const float*)d_in[20];
    float* out = (float*)d_out;

    const int NN = in_sizes[0] / 32;   // 20000
    const int NE = in_sizes[3] / 2;    // 640000
    const int ND = in_sizes[4] / 2;    // 100000

    float* B0 = (float*)d_ws;
    float* B1 = B0 + (size_t)NN * 128;
    float* B2 = B1 + (size_t)NN * 128;
    float* B3 = B2 + (size_t)NN * 128;
    int* cnt  = (int*)(B3 + (size_t)NN * 128);
    int* fill = cnt + NN;
    int* perm = fill + NN;
    int* ssrc = perm + NE;
    int* sdst = ssrc + NE;

    const int nbN = (NN + 63) / 64;
    const int nbE = (NE + 63) / 64;

    // ---- sort edges by dst ----
    hipMemsetAsync(cnt, 0, NN * sizeof(int), stream);
    hist_kernel<<<(NE + 255) / 256, 256, 0, stream>>>(ei, cnt, NE);
    scan_kernel<<<1, 256, 0, stream>>>(cnt, fill, NN);
    scatter_kernel<<<(NE + 255) / 256, 256, 0, stream>>>(ei, fill, perm, ssrc, sdst, NE);

    encode_nodes_kernel<<<512, 256, 0, stream>>>(node_feats, W_node, b_node, B0, NN);

    // ---- layer 0: hin=B0 ----
    sgemm_kernel<<<nbN, 256, 0, stream>>>(B0, nullptr, Wm[0], nullptr, B1, NN, 128, 0);
    sgemm_kernel<<<nbN, 256, 0, stream>>>(B0, nullptr, Wm[0] + 256 * 128, nullptr, B2, NN, 128, 0);
    hipMemsetAsync(B3, 0, (size_t)NN * 128 * sizeof(float), stream);
    edge_msg_mfma_kernel<<<nbE, 256, 0, stream>>>(edge_feats, perm, ssrc, sdst, W_edge, b_edge,
                                                  Wm[0] + 128 * 128, bm[0], B1, B2, B3, NE);
    sgemm_kernel<<<nbN, 256, 0, stream>>>(B0, B3, Wu[0], bu[0], B1, NN, 256, 1);

    // ---- layer 1: hin=B1 ----
    sgemm_kernel<<<nbN, 256, 0, stream>>>(B1, nullptr, Wm[1], nullptr, B0, NN, 128, 0);
    sgemm_kernel<<<nbN, 256, 0, stream>>>(B1, nullptr, Wm[1] + 256 * 128, nullptr, B2, NN, 128, 0);
    hipMemsetAsync(B3, 0, (size_t)NN * 128 * sizeof(float), stream);
    edge_msg_mfma_kernel<<<nbE, 256, 0, stream>>>(edge_feats, perm, ssrc, sdst, W_edge, b_edge,
                                                  Wm[1] + 128 * 128, bm[1], B0, B2, B3, NE);
    sgemm_kernel<<<nbN, 256, 0, stream>>>(B1, B3, Wu[1], bu[1], B2, NN, 256, 1);

    // ---- readout ----
    sgemm_kernel<<<nbN, 256, 0, stream>>>(B2, nullptr, W_r1, nullptr, B0, NN, 128, 0);
    sgemm_kernel<<<nbN, 256, 0, stream>>>(B2, nullptr, W_r1 + 128 * 128, nullptr, B1, NN, 128, 0);
    readout_kernel<<<1024, 256, 0, stream>>>(B0, B1, demand_feats, dp,
                                             W_r1 + 256 * 128, b_r1, W_r2, b_r2, out, ND);
}

// Round 7
// 837.819 us; speedup vs baseline: 3.1013x; 1.2425x over previous
//
#include <hip/hip_runtime.h>
#include <hip/hip_bf16.h>

using short8  = __attribute__((ext_vector_type(8))) short;
using float4v = __attribute__((ext_vector_type(4))) float;

__device__ __forceinline__ float4 f4zero() { return make_float4(0.f, 0.f, 0.f, 0.f); }

__device__ __forceinline__ void fma4(float4& a, float s, const float4& wv) {
    a.x = fmaf(s, wv.x, a.x);
    a.y = fmaf(s, wv.y, a.y);
    a.z = fmaf(s, wv.z, a.z);
    a.w = fmaf(s, wv.w, a.w);
}

__device__ __forceinline__ float bfhi2f(unsigned short u) {
    return __uint_as_float(((unsigned int)u) << 16);
}
__device__ __forceinline__ unsigned short f2bf_rn(float x) {
    unsigned int u = __float_as_uint(x);
    u += 0x7FFFu + ((u >> 16) & 1u);
    return (unsigned short)(u >> 16);
}
__device__ __forceinline__ void split_bf(float v, unsigned short& h, unsigned short& l) {
    h = f2bf_rn(v);
    l = f2bf_rn(v - bfhi2f(h));
}
__device__ __forceinline__ short8 ld_s8(const unsigned short* p) {   // 16B-aligned
    return *(const short8*)p;
}

// ---------------- weight prep: W[K][N] -> hi/lo bf16, transposed [N][Kpad], zero-padded ----------------
__global__ __launch_bounds__(256) void tsplit_kernel(
    const float* __restrict__ W, int K, int N, int Kpad,
    unsigned short* __restrict__ oh, unsigned short* __restrict__ ol)
{
    const int idx = blockIdx.x * 256 + threadIdx.x;
    if (idx >= N * Kpad) return;
    const int n = idx / Kpad, k = idx - n * Kpad;
    const float v = (k < K) ? W[(size_t)k * N + n] : 0.f;
    unsigned short h, l;
    split_bf(v, h, l);
    oh[idx] = h; ol[idx] = l;
}

// ---------------- sort pipeline: counting sort of edges by dst ----------------
__global__ __launch_bounds__(256) void hist_kernel(
    const int* __restrict__ ei, int* __restrict__ cnt, int E)
{
    const int i = blockIdx.x * blockDim.x + threadIdx.x;
    if (i < E) atomicAdd(&cnt[ei[E + i]], 1);
}

__global__ __launch_bounds__(256) void scan_kernel(
    const int* __restrict__ cnt, int* __restrict__ fill, int n)
{
    __shared__ int part[256];
    const int tid = threadIdx.x;
    const int chunk = (n + 255) / 256;
    const int beg = tid * chunk;
    const int end = min(beg + chunk, n);
    int s = 0;
    for (int i = beg; i < end; ++i) s += cnt[i];
    part[tid] = s;
    __syncthreads();
    for (int off = 1; off < 256; off <<= 1) {
        const int v = (tid >= off) ? part[tid - off] : 0;
        __syncthreads();
        part[tid] += v;
        __syncthreads();
    }
    int prefix = (tid == 0) ? 0 : part[tid - 1];
    for (int i = beg; i < end; ++i) { fill[i] = prefix; prefix += cnt[i]; }
}

__global__ __launch_bounds__(256) void scatter_kernel(
    const int* __restrict__ ei, int* __restrict__ fill,
    int* __restrict__ perm, int* __restrict__ ssrc, int* __restrict__ sdst, int E)
{
    const int e = blockIdx.x * blockDim.x + threadIdx.x;
    if (e < E) {
        const int d = ei[E + e];
        const int pos = atomicAdd(&fill[d], 1);
        perm[pos] = e;
        ssrc[pos] = ei[e];
        sdst[pos] = d;
    }
}

// ---------------- encode: h = relu(X[M,32] @ W[32,128] + b) ----------------
__global__ __launch_bounds__(256) void encode_nodes_kernel(
    const float* __restrict__ X, const float* __restrict__ W,
    const float* __restrict__ bias, float* __restrict__ out, int M)
{
    __shared__ float w[32 * 128];
    __shared__ float xs[2][32];
    const int tid = threadIdx.x;
    const int j = tid & 127;
    const int slot = tid >> 7;
    for (int idx = tid; idx < 32 * 128; idx += 256) w[idx] = W[idx];
    __syncthreads();
    const float bj = bias[j];
    for (int r0 = blockIdx.x * 2; r0 < M; r0 += gridDim.x * 2) {
        const int r = r0 + slot;
        const bool valid = r < M;
        if (valid && j < 32) xs[slot][j] = X[(size_t)r * 32 + j];
        __syncthreads();
        if (valid) {
            float a = bj;
#pragma unroll
            for (int k = 0; k < 32; ++k) a = fmaf(xs[slot][k], w[k * 128 + j], a);
            out[(size_t)r * 128 + j] = fmaxf(a, 0.f);
        }
        __syncthreads();
    }
}

// ---- C[M,128] = act( [A1 | A2][M,K] @ W[K,128] + bias ), K in {128,256} ----
__global__ __launch_bounds__(256) void sgemm_kernel(
    const float* __restrict__ A1, const float* __restrict__ A2,
    const float* __restrict__ W, const float* __restrict__ bias,
    float* __restrict__ C, int M, int K, int relu_flag)
{
    __shared__ float Xt[64 * 68];
    __shared__ float Ws[64 * 128];
    const int tid = threadIdx.x;
    const int tx = tid & 31;
    const int ty = tid >> 5;
    const int r0 = blockIdx.x * 64;

    float4 acc[8];
#pragma unroll
    for (int i = 0; i < 8; ++i) acc[i] = f4zero();

    for (int k0 = 0; k0 < K; k0 += 64) {
        const float* A = (k0 < 128) ? A1 : A2;
        const int kb = k0 & 127;
        __syncthreads();
#pragma unroll
        for (int rep = 0; rep < 4; ++rep) {
            const int fid = tid + rep * 256;
            const int row = fid >> 4, kq = fid & 15;
            float4 v = f4zero();
            const int r = r0 + row;
            if (r < M) v = *(const float4*)&A[(size_t)r * 128 + kb + 4 * kq];
            Xt[(4 * kq + 0) * 68 + row] = v.x;
            Xt[(4 * kq + 1) * 68 + row] = v.y;
            Xt[(4 * kq + 2) * 68 + row] = v.z;
            Xt[(4 * kq + 3) * 68 + row] = v.w;
        }
#pragma unroll
        for (int rep = 0; rep < 8; ++rep) {
            const int fid = tid + rep * 256;
            const int row = fid >> 5, cq = fid & 31;
            *(float4*)&Ws[row * 128 + 4 * cq] =
                *(const float4*)&W[(size_t)(k0 + row) * 128 + 4 * cq];
        }
        __syncthreads();
#pragma unroll 4
        for (int kk = 0; kk < 64; ++kk) {
            const float4 w4 = *(const float4*)&Ws[kk * 128 + 4 * tx];
            const float4 xa = *(const float4*)&Xt[kk * 68 + 8 * ty];
            const float4 xb = *(const float4*)&Xt[kk * 68 + 8 * ty + 4];
            fma4(acc[0], xa.x, w4); fma4(acc[1], xa.y, w4);
            fma4(acc[2], xa.z, w4); fma4(acc[3], xa.w, w4);
            fma4(acc[4], xb.x, w4); fma4(acc[5], xb.y, w4);
            fma4(acc[6], xb.z, w4); fma4(acc[7], xb.w, w4);
        }
    }
    float4 b4 = f4zero();
    if (bias) b4 = *(const float4*)&bias[4 * tx];
#pragma unroll
    for (int i = 0; i < 8; ++i) {
        const int r = r0 + 8 * ty + i;
        if (r < M) {
            float4 v;
            v.x = acc[i].x + b4.x; v.y = acc[i].y + b4.y;
            v.z = acc[i].z + b4.z; v.w = acc[i].w + b4.w;
            if (relu_flag) {
                v.x = fmaxf(v.x, 0.f); v.y = fmaxf(v.y, 0.f);
                v.z = fmaxf(v.z, 0.f); v.w = fmaxf(v.w, 0.f);
            }
            *(float4*)&C[(size_t)r * 128 + 4 * tx] = v;
        }
    }
}

// ---- fused edge path, split-bf16 MFMA, pre-split weights from global ----
// wehT_h/l: We transposed [n=128][k=32] (k>=16 zeroed). wmT_h/l: Wmid transposed [n=128][k=128].
__global__ __launch_bounds__(256) void edge_msg_mfma_kernel(
    const float* __restrict__ edge_feats,
    const int* __restrict__ perm, const int* __restrict__ ssrc, const int* __restrict__ sdst,
    const unsigned short* __restrict__ wehT_h, const unsigned short* __restrict__ wehT_l,
    const float* __restrict__ be,
    const unsigned short* __restrict__ wmT_h, const unsigned short* __restrict__ wmT_l,
    const float* __restrict__ bm,
    const float* __restrict__ Psrc, const float* __restrict__ Pdst,
    float* __restrict__ agg, int E)
{
    // LDS (bytes):
    //     0: ahi [64][136] u16 (17408)   he hi, row-major [m][k], stride 136
    // 17408: alo [64][136] u16 (17408)
    // 34816: efh [64][40]  u16 ( 5120)   edge feats hi, k 16..31 zeroed
    // 39936: efl [64][40]  u16 ( 5120)
    // 45056: sdh[64] int | 45312: ssh[64] int   -> 45568 total
    // ms[64][132] f32 (33792) overlays ahi/alo after mid GEMM.
    __shared__ __align__(16) char smem[45568];
    unsigned short* ahi = (unsigned short*)smem;
    unsigned short* alo = (unsigned short*)(smem + 17408);
    unsigned short* efh = (unsigned short*)(smem + 34816);
    unsigned short* efl = (unsigned short*)(smem + 39936);
    int* sdh = (int*)(smem + 45056);
    int* ssh = (int*)(smem + 45312);
    float* ms = (float*)smem;

    const int tid = threadIdx.x;
    const int w = tid >> 6;          // wave 0..3
    const int l = tid & 63;
    const int quad = l >> 4;
    const int l16 = l & 15;
    const int p0 = blockIdx.x * 64;

    if (tid < 64) {
        const int p = p0 + tid;
        sdh[tid] = (p < E) ? sdst[p] : -1;
        ssh[tid] = (p < E) ? ssrc[p] : 0;
    }
    // zero ef pad k=16..31
    {
        const int row = tid >> 2, k16 = 16 + (tid & 3) * 4;
        *(ulong1*)&efh[row * 40 + k16] = ulong1{0};
        *(ulong1*)&efl[row * 40 + k16] = ulong1{0};
    }
    // stage edge feats (gather via perm), split hi/lo
    {
        const int row = tid >> 2, c4 = (tid & 3) * 4;
        const int p = p0 + row;
        float4 v = f4zero();
        if (p < E) {
            const int e = perm[p];
            v = *(const float4*)&edge_feats[(size_t)e * 16 + c4];
        }
        unsigned short h, lo;
        split_bf(v.x, h, lo); efh[row * 40 + c4 + 0] = h; efl[row * 40 + c4 + 0] = lo;
        split_bf(v.y, h, lo); efh[row * 40 + c4 + 1] = h; efl[row * 40 + c4 + 1] = lo;
        split_bf(v.z, h, lo); efh[row * 40 + c4 + 2] = h; efl[row * 40 + c4 + 2] = lo;
        split_bf(v.w, h, lo); efh[row * 40 + c4 + 3] = h; efl[row * 40 + c4 + 3] = lo;
    }
    __syncthreads();

    float4v acc[4][2];
#pragma unroll
    for (int mt = 0; mt < 4; ++mt)
#pragma unroll
        for (int t = 0; t < 2; ++t) acc[mt][t] = (float4v)0.f;

    // ---- he phase: MFMA over K=32 (zero-padded) ----
    {
        short8 bh[2], bl[2];
#pragma unroll
        for (int t = 0; t < 2; ++t) {
            const int g = ((2 * w + t) * 16 + l16) * 32 + quad * 8;
            bh[t] = ld_s8(&wehT_h[g]);
            bl[t] = ld_s8(&wehT_l[g]);
        }
#pragma unroll
        for (int mt = 0; mt < 4; ++mt) {
            const int base = (mt * 16 + l16) * 40 + quad * 8;
            const short8 ah = ld_s8(&efh[base]);
            const short8 al = ld_s8(&efl[base]);
#pragma unroll
            for (int t = 0; t < 2; ++t) {
                acc[mt][t] = __builtin_amdgcn_mfma_f32_16x16x32_bf16(ah, bh[t], acc[mt][t], 0, 0, 0);
                acc[mt][t] = __builtin_amdgcn_mfma_f32_16x16x32_bf16(ah, bl[t], acc[mt][t], 0, 0, 0);
                acc[mt][t] = __builtin_amdgcn_mfma_f32_16x16x32_bf16(al, bh[t], acc[mt][t], 0, 0, 0);
            }
        }
        // bias + relu + split -> ahi/alo (A operand of mid GEMM)
#pragma unroll
        for (int t = 0; t < 2; ++t) {
            const int col = (2 * w + t) * 16 + l16;
            const float bcol = be[col];
#pragma unroll
            for (int mt = 0; mt < 4; ++mt)
#pragma unroll
                for (int r = 0; r < 4; ++r) {
                    const int row = mt * 16 + quad * 4 + r;
                    const float v = fmaxf(acc[mt][t][r] + bcol, 0.f);
                    unsigned short h, lo;
                    split_bf(v, h, lo);
                    ahi[row * 136 + col] = h;
                    alo[row * 136 + col] = lo;
                }
        }
    }
    __syncthreads();

    // ---- mid GEMM: K=128 in 4 chunks of 32; B direct from global, no barriers ----
#pragma unroll
    for (int mt = 0; mt < 4; ++mt)
#pragma unroll
        for (int t = 0; t < 2; ++t) acc[mt][t] = (float4v)0.f;

#pragma unroll
    for (int c = 0; c < 4; ++c) {
        const int k0 = c * 32;
        short8 bh[2], bl[2];
#pragma unroll
        for (int t = 0; t < 2; ++t) {
            const int g = ((2 * w + t) * 16 + l16) * 128 + k0 + quad * 8;
            bh[t] = ld_s8(&wmT_h[g]);
            bl[t] = ld_s8(&wmT_l[g]);
        }
#pragma unroll
        for (int mt = 0; mt < 4; ++mt) {
            const int base = (mt * 16 + l16) * 136 + k0 + quad * 8;
            const short8 ah = ld_s8(&ahi[base]);
            const short8 al = ld_s8(&alo[base]);
#pragma unroll
            for (int t = 0; t < 2; ++t) {
                acc[mt][t] = __builtin_amdgcn_mfma_f32_16x16x32_bf16(ah, bh[t], acc[mt][t], 0, 0, 0);
                acc[mt][t] = __builtin_amdgcn_mfma_f32_16x16x32_bf16(ah, bl[t], acc[mt][t], 0, 0, 0);
                acc[mt][t] = __builtin_amdgcn_mfma_f32_16x16x32_bf16(al, bh[t], acc[mt][t], 0, 0, 0);
            }
        }
    }
    __syncthreads();   // all ahi/alo reads done; safe to overlay ms

    // ---- spill mid to ms[64][132] ----
#pragma unroll
    for (int mt = 0; mt < 4; ++mt)
#pragma unroll
        for (int t = 0; t < 2; ++t) {
            const int col = (2 * w + t) * 16 + l16;
#pragma unroll
            for (int r = 0; r < 4; ++r)
                ms[(mt * 16 + quad * 4 + r) * 132 + col] = acc[mt][t][r];
        }
    __syncthreads();

    // ---- epilogue: + bm + Ps[src] + Pd[dst], relu ----
    {
        const int tx = tid & 31, ty = tid >> 5;
        const float4 bm4 = *(const float4*)&bm[4 * tx];
#pragma unroll
        for (int i = 0; i < 8; ++i) {
            const int row = 8 * ty + i;
            const int p = p0 + row;
            if (p < E) {
                const int s = ssh[row];
                const int d = sdh[row];
                const float4 ps = *(const float4*)&Psrc[(size_t)s * 128 + 4 * tx];
                const float4 pd = *(const float4*)&Pdst[(size_t)d * 128 + 4 * tx];
                float4 m4 = *(const float4*)&ms[row * 132 + 4 * tx];
                m4.x = fmaxf(m4.x + bm4.x + ps.x + pd.x, 0.f);
                m4.y = fmaxf(m4.y + bm4.y + ps.y + pd.y, 0.f);
                m4.z = fmaxf(m4.z + bm4.z + ps.z + pd.z, 0.f);
                m4.w = fmaxf(m4.w + bm4.w + ps.w + pd.w, 0.f);
                *(float4*)&ms[row * 132 + 4 * tx] = m4;
            }
        }
    }
    __syncthreads();

    // ---- run-length segmented reduction: one atomic per dst-run per column ----
    {
        const int j = tid & 127;
        const int base = (tid < 128) ? 0 : 32;
        float a = 0.f;
        for (int r = base; r < base + 32; ++r) {
            const int d = sdh[r];
            if (d < 0) break;
            a += ms[r * 132 + j];
            if (r == base + 31 || sdh[r + 1] != d) {
                atomicAdd(&agg[(size_t)d * 128 + j], a);
                a = 0.f;
            }
        }
    }
}

// ---- readout ----
__global__ __launch_bounds__(256) void readout_kernel(
    const float* __restrict__ Qs, const float* __restrict__ Qd,
    const float* __restrict__ df, const int* __restrict__ dp,
    const float* __restrict__ Wd, const float* __restrict__ b1,
    const float* __restrict__ w2, const float* __restrict__ b2,
    float* __restrict__ out, int D)
{
    __shared__ float wd[8 * 128];
    __shared__ float partial[4];
    const int tid = threadIdx.x;
    const int j = tid & 127;
    const int slot = tid >> 7;
    for (int idx = tid; idx < 8 * 128; idx += 256) wd[idx] = Wd[idx];
    __syncthreads();
    const float bj = b1[j];
    const float w2j = w2[j];
    const float bb = b2[0];
    for (int d0 = blockIdx.x * 2; d0 < D; d0 += gridDim.x * 2) {
        const int d = d0 + slot;
        const bool valid = d < D;
        float v = 0.f;
        if (valid) {
            const int s = dp[2 * d], t = dp[2 * d + 1];
            float a = bj + Qs[(size_t)s * 128 + j] + Qd[(size_t)t * 128 + j];
#pragma unroll
            for (int k = 0; k < 8; ++k) a = fmaf(df[(size_t)d * 8 + k], wd[k * 128 + j], a);
            v = fmaxf(a, 0.f) * w2j;
        }
        for (int o = 32; o > 0; o >>= 1) v += __shfl_down(v, o);
        if ((tid & 63) == 0) partial[tid >> 6] = v;
        __syncthreads();
        if (valid && j == 0) {
            const float tot = partial[slot * 2] + partial[slot * 2 + 1] + bb;
            out[d] = 1.f / (1.f + __expf(-tot));
        }
        __syncthreads();
    }
}

extern "C" void kernel_launch(void* const* d_in, const int* in_sizes, int n_in,
                              void* d_out, int out_size, void* d_ws, size_t ws_size,
                              hipStream_t stream)
{
    const float* node_feats   = (const float*)d_in[0];
    const float* edge_feats   = (const float*)d_in[1];
    const float* demand_feats = (const float*)d_in[2];
    const int*   ei = (const int*)d_in[3];
    const int*   dp = (const int*)d_in[4];
    const float* W_node = (const float*)d_in[5];
    const float* b_node = (const float*)d_in[6];
    const float* W_edge = (const float*)d_in[7];
    const float* b_edge = (const float*)d_in[8];
    const float* Wm[2] = {(const float*)d_in[9],  (const float*)d_in[13]};
    const float* bm[2] = {(const float*)d_in[10], (const float*)d_in[14]};
    const float* Wu[2] = {(const float*)d_in[11], (const float*)d_in[15]};
    const float* bu[2] = {(const float*)d_in[12], (const float*)d_in[16]};
    const float* W_r1 = (const float*)d_in[17];
    const float* b_r1 = (const float*)d_in[18];
    const float* W_r2 = (const float*)d_in[19];
    const float* b_r2 = (const float*)d_in[20];
    float* out = (float*)d_out;

    const int NN = in_sizes[0] / 32;   // 20000
    const int NE = in_sizes[3] / 2;    // 640000
    const int ND = in_sizes[4] / 2;    // 100000

    float* B0 = (float*)d_ws;
    float* B1 = B0 + (size_t)NN * 128;
    float* B2 = B1 + (size_t)NN * 128;
    float* B3 = B2 + (size_t)NN * 128;
    int* cnt  = (int*)(B3 + (size_t)NN * 128);
    int* fill = cnt + NN;
    int* perm = fill + NN;
    int* ssrc = perm + NE;
    int* sdst = ssrc + NE;
    unsigned short* wehT_h = (unsigned short*)(sdst + NE);
    unsigned short* wehT_l = wehT_h + 128 * 32;
    unsigned short* wm0_h  = wehT_l + 128 * 32;
    unsigned short* wm0_l  = wm0_h + 128 * 128;
    unsigned short* wm1_h  = wm0_l + 128 * 128;
    unsigned short* wm1_l  = wm1_h + 128 * 128;

    const int nbN = (NN + 63) / 64;
    const int nbE = (NE + 63) / 64;

    // ---- weight prep (once per launch) ----
    tsplit_kernel<<<16, 256, 0, stream>>>(W_edge, 16, 128, 32, wehT_h, wehT_l);
    tsplit_kernel<<<64, 256, 0, stream>>>(Wm[0] + 128 * 128, 128, 128, 128, wm0_h, wm0_l);
    tsplit_kernel<<<64, 256, 0, stream>>>(Wm[1] + 128 * 128, 128, 128, 128, wm1_h, wm1_l);

    // ---- sort edges by dst ----
    hipMemsetAsync(cnt, 0, NN * sizeof(int), stream);
    hist_kernel<<<(NE + 255) / 256, 256, 0, stream>>>(ei, cnt, NE);
    scan_kernel<<<1, 256, 0, stream>>>(cnt, fill, NN);
    scatter_kernel<<<(NE + 255) / 256, 256, 0, stream>>>(ei, fill, perm, ssrc, sdst, NE);

    encode_nodes_kernel<<<512, 256, 0, stream>>>(node_feats, W_node, b_node, B0, NN);

    // ---- layer 0: hin=B0 ----
    sgemm_kernel<<<nbN, 256, 0, stream>>>(B0, nullptr, Wm[0], nullptr, B1, NN, 128, 0);
    sgemm_kernel<<<nbN, 256, 0, stream>>>(B0, nullptr, Wm[0] + 256 * 128, nullptr, B2, NN, 128, 0);
    hipMemsetAsync(B3, 0, (size_t)NN * 128 * sizeof(float), stream);
    edge_msg_mfma_kernel<<<nbE, 256, 0, stream>>>(edge_feats, perm, ssrc, sdst,
                                                  wehT_h, wehT_l, b_edge,
                                                  wm0_h, wm0_l, bm[0], B1, B2, B3, NE);
    sgemm_kernel<<<nbN, 256, 0, stream>>>(B0, B3, Wu[0], bu[0], B1, NN, 256, 1);

    // ---- layer 1: hin=B1 ----
    sgemm_kernel<<<nbN, 256, 0, stream>>>(B1, nullptr, Wm[1], nullptr, B0, NN, 128, 0);
    sgemm_kernel<<<nbN, 256, 0, stream>>>(B1, nullptr, Wm[1] + 256 * 128, nullptr, B2, NN, 128, 0);
    hipMemsetAsync(B3, 0, (size_t)NN * 128 * sizeof(float), stream);
    edge_msg_mfma_kernel<<<nbE, 256, 0, stream>>>(edge_feats, perm, ssrc, sdst,
                                                  wehT_h, wehT_l, b_edge,
                                                  wm1_h, wm1_l, bm[1], B0, B2, B3, NE);
    sgemm_kernel<<<nbN, 256, 0, stream>>>(B1, B3, Wu[1], bu[1], B2, NN, 256, 1);

    // ---- readout ----
    sgemm_kernel<<<nbN, 256, 0, stream>>>(B2, nullptr, W_r1, nullptr, B0, NN, 128, 0);
    sgemm_kernel<<<nbN, 256, 0, stream>>>(B2, nullptr, W_r1 + 128 * 128, nullptr, B1, NN, 128, 0);
    readout_kernel<<<1024, 256, 0, stream>>>(B0, B1, demand_feats, dp,
                                             W_r1 + 256 * 128, b_r1, W_r2, b_r2, out, ND);
}

// Round 8
// 828.868 us; speedup vs baseline: 3.1348x; 1.0108x over previous
//
#include <hip/hip_runtime.h>
#include <hip/hip_bf16.h>

using short8  = __attribute__((ext_vector_type(8))) short;
using float4v = __attribute__((ext_vector_type(4))) float;

__device__ __forceinline__ float4 f4zero() { return make_float4(0.f, 0.f, 0.f, 0.f); }

__device__ __forceinline__ void fma4(float4& a, float s, const float4& wv) {
    a.x = fmaf(s, wv.x, a.x);
    a.y = fmaf(s, wv.y, a.y);
    a.z = fmaf(s, wv.z, a.z);
    a.w = fmaf(s, wv.w, a.w);
}

__device__ __forceinline__ float bfhi2f(unsigned short u) {
    return __uint_as_float(((unsigned int)u) << 16);
}
__device__ __forceinline__ unsigned short f2bf_rn(float x) {
    unsigned int u = __float_as_uint(x);
    u += 0x7FFFu + ((u >> 16) & 1u);
    return (unsigned short)(u >> 16);
}
__device__ __forceinline__ void split_bf(float v, unsigned short& h, unsigned short& l) {
    h = f2bf_rn(v);
    l = f2bf_rn(v - bfhi2f(h));
}
__device__ __forceinline__ short8 ld_s8(const unsigned short* p) {   // 16B-aligned
    return *(const short8*)p;
}

// ---------------- weight prep: W[K][N] -> hi/lo bf16, transposed [N][Kpad] ----------------
__global__ __launch_bounds__(256) void tsplit_kernel(
    const float* __restrict__ W, int K, int N, int Kpad,
    unsigned short* __restrict__ oh, unsigned short* __restrict__ ol)
{
    const int idx = blockIdx.x * 256 + threadIdx.x;
    if (idx >= N * Kpad) return;
    const int n = idx / Kpad, k = idx - n * Kpad;
    const float v = (k < K) ? W[(size_t)k * N + n] : 0.f;
    unsigned short h, l;
    split_bf(v, h, l);
    oh[idx] = h; ol[idx] = l;
}

// ---------------- sort pipeline ----------------
__global__ __launch_bounds__(256) void hist_kernel(
    const int* __restrict__ ei, int* __restrict__ cnt, int E)
{
    const int i = blockIdx.x * blockDim.x + threadIdx.x;
    if (i < E) atomicAdd(&cnt[ei[E + i]], 1);
}

__global__ __launch_bounds__(256) void scan_kernel(
    const int* __restrict__ cnt, int* __restrict__ fill, int n)
{
    __shared__ int part[256];
    const int tid = threadIdx.x;
    const int chunk = (n + 255) / 256;
    const int beg = tid * chunk;
    const int end = min(beg + chunk, n);
    int s = 0;
    for (int i = beg; i < end; ++i) s += cnt[i];
    part[tid] = s;
    __syncthreads();
    for (int off = 1; off < 256; off <<= 1) {
        const int v = (tid >= off) ? part[tid - off] : 0;
        __syncthreads();
        part[tid] += v;
        __syncthreads();
    }
    int prefix = (tid == 0) ? 0 : part[tid - 1];
    for (int i = beg; i < end; ++i) { fill[i] = prefix; prefix += cnt[i]; }
}

__global__ __launch_bounds__(256) void scatter_kernel(
    const int* __restrict__ ei, int* __restrict__ fill,
    int* __restrict__ perm, int* __restrict__ ssrc, int* __restrict__ sdst, int E)
{
    const int e = blockIdx.x * blockDim.x + threadIdx.x;
    if (e < E) {
        const int d = ei[E + e];
        const int pos = atomicAdd(&fill[d], 1);
        perm[pos] = e;
        ssrc[pos] = ei[e];
        sdst[pos] = d;
    }
}

// ---------------- encode: h = relu(X[M,32] @ W[32,128] + b) ----------------
__global__ __launch_bounds__(256) void encode_nodes_kernel(
    const float* __restrict__ X, const float* __restrict__ W,
    const float* __restrict__ bias, float* __restrict__ out, int M)
{
    __shared__ float w[32 * 128];
    __shared__ float xs[2][32];
    const int tid = threadIdx.x;
    const int j = tid & 127;
    const int slot = tid >> 7;
    for (int idx = tid; idx < 32 * 128; idx += 256) w[idx] = W[idx];
    __syncthreads();
    const float bj = bias[j];
    for (int r0 = blockIdx.x * 2; r0 < M; r0 += gridDim.x * 2) {
        const int r = r0 + slot;
        const bool valid = r < M;
        if (valid && j < 32) xs[slot][j] = X[(size_t)r * 32 + j];
        __syncthreads();
        if (valid) {
            float a = bj;
#pragma unroll
            for (int k = 0; k < 32; ++k) a = fmaf(xs[slot][k], w[k * 128 + j], a);
            out[(size_t)r * 128 + j] = fmaxf(a, 0.f);
        }
        __syncthreads();
    }
}

// ---- C[M,128] = act( [A1 | A2][M,K] @ W[K,128] + bias ), K in {128,256} ----
__global__ __launch_bounds__(256) void sgemm_kernel(
    const float* __restrict__ A1, const float* __restrict__ A2,
    const float* __restrict__ W, const float* __restrict__ bias,
    float* __restrict__ C, int M, int K, int relu_flag)
{
    __shared__ float Xt[64 * 68];
    __shared__ float Ws[64 * 128];
    const int tid = threadIdx.x;
    const int tx = tid & 31;
    const int ty = tid >> 5;
    const int r0 = blockIdx.x * 64;

    float4 acc[8];
#pragma unroll
    for (int i = 0; i < 8; ++i) acc[i] = f4zero();

    for (int k0 = 0; k0 < K; k0 += 64) {
        const float* A = (k0 < 128) ? A1 : A2;
        const int kb = k0 & 127;
        __syncthreads();
#pragma unroll
        for (int rep = 0; rep < 4; ++rep) {
            const int fid = tid + rep * 256;
            const int row = fid >> 4, kq = fid & 15;
            float4 v = f4zero();
            const int r = r0 + row;
            if (r < M) v = *(const float4*)&A[(size_t)r * 128 + kb + 4 * kq];
            Xt[(4 * kq + 0) * 68 + row] = v.x;
            Xt[(4 * kq + 1) * 68 + row] = v.y;
            Xt[(4 * kq + 2) * 68 + row] = v.z;
            Xt[(4 * kq + 3) * 68 + row] = v.w;
        }
#pragma unroll
        for (int rep = 0; rep < 8; ++rep) {
            const int fid = tid + rep * 256;
            const int row = fid >> 5, cq = fid & 31;
            *(float4*)&Ws[row * 128 + 4 * cq] =
                *(const float4*)&W[(size_t)(k0 + row) * 128 + 4 * cq];
        }
        __syncthreads();
#pragma unroll 4
        for (int kk = 0; kk < 64; ++kk) {
            const float4 w4 = *(const float4*)&Ws[kk * 128 + 4 * tx];
            const float4 xa = *(const float4*)&Xt[kk * 68 + 8 * ty];
            const float4 xb = *(const float4*)&Xt[kk * 68 + 8 * ty + 4];
            fma4(acc[0], xa.x, w4); fma4(acc[1], xa.y, w4);
            fma4(acc[2], xa.z, w4); fma4(acc[3], xa.w, w4);
            fma4(acc[4], xb.x, w4); fma4(acc[5], xb.y, w4);
            fma4(acc[6], xb.z, w4); fma4(acc[7], xb.w, w4);
        }
    }
    float4 b4 = f4zero();
    if (bias) b4 = *(const float4*)&bias[4 * tx];
#pragma unroll
    for (int i = 0; i < 8; ++i) {
        const int r = r0 + 8 * ty + i;
        if (r < M) {
            float4 v;
            v.x = acc[i].x + b4.x; v.y = acc[i].y + b4.y;
            v.z = acc[i].z + b4.z; v.w = acc[i].w + b4.w;
            if (relu_flag) {
                v.x = fmaxf(v.x, 0.f); v.y = fmaxf(v.y, 0.f);
                v.z = fmaxf(v.z, 0.f); v.w = fmaxf(v.w, 0.f);
            }
            *(float4*)&C[(size_t)r * 128 + 4 * tx] = v;
        }
    }
}

// ---- C1 = A@W1, C2 = A@W2 (K=128, no bias/act) — fused paired projections ----
__global__ __launch_bounds__(256) void sgemm_dual_kernel(
    const float* __restrict__ A,
    const float* __restrict__ W1, const float* __restrict__ W2,
    float* __restrict__ C1, float* __restrict__ C2, int M)
{
    __shared__ float Xt[32 * 68];     // [k 32][row 64]
    __shared__ float Ws1[32 * 128];
    __shared__ float Ws2[32 * 128];
    const int tid = threadIdx.x;
    const int tx = tid & 31;
    const int ty = tid >> 5;
    const int r0 = blockIdx.x * 64;

    float4 a1[8], a2[8];
#pragma unroll
    for (int i = 0; i < 8; ++i) { a1[i] = f4zero(); a2[i] = f4zero(); }

    for (int k0 = 0; k0 < 128; k0 += 32) {
        __syncthreads();
        // A chunk: 64 rows x 32 k = 512 float4 (2 reps)
#pragma unroll
        for (int rep = 0; rep < 2; ++rep) {
            const int fid = tid + rep * 256;
            const int row = fid >> 3, kq = fid & 7;
            float4 v = f4zero();
            const int r = r0 + row;
            if (r < M) v = *(const float4*)&A[(size_t)r * 128 + k0 + 4 * kq];
            Xt[(4 * kq + 0) * 68 + row] = v.x;
            Xt[(4 * kq + 1) * 68 + row] = v.y;
            Xt[(4 * kq + 2) * 68 + row] = v.z;
            Xt[(4 * kq + 3) * 68 + row] = v.w;
        }
        // W chunks: 32x128 = 1024 float4 each (4 reps)
#pragma unroll
        for (int rep = 0; rep < 4; ++rep) {
            const int fid = tid + rep * 256;
            const int row = fid >> 5, cq = fid & 31;
            *(float4*)&Ws1[row * 128 + 4 * cq] =
                *(const float4*)&W1[(size_t)(k0 + row) * 128 + 4 * cq];
            *(float4*)&Ws2[row * 128 + 4 * cq] =
                *(const float4*)&W2[(size_t)(k0 + row) * 128 + 4 * cq];
        }
        __syncthreads();
#pragma unroll 4
        for (int kk = 0; kk < 32; ++kk) {
            const float4 w1 = *(const float4*)&Ws1[kk * 128 + 4 * tx];
            const float4 w2 = *(const float4*)&Ws2[kk * 128 + 4 * tx];
            const float4 xa = *(const float4*)&Xt[kk * 68 + 8 * ty];
            const float4 xb = *(const float4*)&Xt[kk * 68 + 8 * ty + 4];
            fma4(a1[0], xa.x, w1); fma4(a1[1], xa.y, w1);
            fma4(a1[2], xa.z, w1); fma4(a1[3], xa.w, w1);
            fma4(a1[4], xb.x, w1); fma4(a1[5], xb.y, w1);
            fma4(a1[6], xb.z, w1); fma4(a1[7], xb.w, w1);
            fma4(a2[0], xa.x, w2); fma4(a2[1], xa.y, w2);
            fma4(a2[2], xa.z, w2); fma4(a2[3], xa.w, w2);
            fma4(a2[4], xb.x, w2); fma4(a2[5], xb.y, w2);
            fma4(a2[6], xb.z, w2); fma4(a2[7], xb.w, w2);
        }
    }
#pragma unroll
    for (int i = 0; i < 8; ++i) {
        const int r = r0 + 8 * ty + i;
        if (r < M) {
            *(float4*)&C1[(size_t)r * 128 + 4 * tx] = a1[i];
            *(float4*)&C2[(size_t)r * 128 + 4 * tx] = a2[i];
        }
    }
}

// ---- fused edge path, split-bf16 MFMA, pre-split weights, register-prefetched gathers ----
__global__ __launch_bounds__(256, 3) void edge_msg_mfma_kernel(
    const float* __restrict__ edge_feats,
    const int* __restrict__ perm, const int* __restrict__ ssrc, const int* __restrict__ sdst,
    const unsigned short* __restrict__ wehT_h, const unsigned short* __restrict__ wehT_l,
    const float* __restrict__ be,
    const unsigned short* __restrict__ wmT_h, const unsigned short* __restrict__ wmT_l,
    const float* __restrict__ bm,
    const float* __restrict__ Psrc, const float* __restrict__ Pdst,
    float* __restrict__ agg, int E)
{
    __shared__ __align__(16) char smem[45568];
    unsigned short* ahi = (unsigned short*)smem;            // [64][136] u16
    unsigned short* alo = (unsigned short*)(smem + 17408);  // [64][136] u16
    unsigned short* efh = (unsigned short*)(smem + 34816);  // [64][40] u16
    unsigned short* efl = (unsigned short*)(smem + 39936);  // [64][40] u16
    int* sdh = (int*)(smem + 45056);
    int* ssh = (int*)(smem + 45312);
    float* ms = (float*)smem;                               // [64][132] f32 overlay

    const int tid = threadIdx.x;
    const int w = tid >> 6;
    const int l = tid & 63;
    const int quad = l >> 4;
    const int l16 = l & 15;
    const int tx = tid & 31;
    const int ty = tid >> 5;
    const int p0 = blockIdx.x * 64;

    // ---- EARLY: prefetch Psrc/Pdst gathers for the epilogue (rows 8ty+i, cols 4tx..) ----
    float4 psr[8], pdr[8];
#pragma unroll
    for (int i = 0; i < 8; ++i) {
        const int p = p0 + 8 * ty + i;
        const int s = (p < E) ? ssrc[p] : 0;
        const int d = (p < E) ? sdst[p] : 0;
        psr[i] = *(const float4*)&Psrc[(size_t)s * 128 + 4 * tx];
        pdr[i] = *(const float4*)&Pdst[(size_t)d * 128 + 4 * tx];
    }

    if (tid < 64) {
        const int p = p0 + tid;
        sdh[tid] = (p < E) ? sdst[p] : -1;
        ssh[tid] = (p < E) ? ssrc[p] : 0;
    }
    // zero ef pad k=16..31
    {
        const int row = tid >> 2, k16 = 16 + (tid & 3) * 4;
        *(ulong1*)&efh[row * 40 + k16] = ulong1{0};
        *(ulong1*)&efl[row * 40 + k16] = ulong1{0};
    }
    // stage edge feats (gather via perm), split hi/lo
    {
        const int row = tid >> 2, c4 = (tid & 3) * 4;
        const int p = p0 + row;
        float4 v = f4zero();
        if (p < E) {
            const int e = perm[p];
            v = *(const float4*)&edge_feats[(size_t)e * 16 + c4];
        }
        unsigned short h, lo;
        split_bf(v.x, h, lo); efh[row * 40 + c4 + 0] = h; efl[row * 40 + c4 + 0] = lo;
        split_bf(v.y, h, lo); efh[row * 40 + c4 + 1] = h; efl[row * 40 + c4 + 1] = lo;
        split_bf(v.z, h, lo); efh[row * 40 + c4 + 2] = h; efl[row * 40 + c4 + 2] = lo;
        split_bf(v.w, h, lo); efh[row * 40 + c4 + 3] = h; efl[row * 40 + c4 + 3] = lo;
    }
    __syncthreads();

    float4v acc[4][2];
#pragma unroll
    for (int mt = 0; mt < 4; ++mt)
#pragma unroll
        for (int t = 0; t < 2; ++t) acc[mt][t] = (float4v)0.f;

    // ---- he phase: MFMA over K=32 (zero-padded) ----
    {
        short8 bh[2], bl[2];
#pragma unroll
        for (int t = 0; t < 2; ++t) {
            const int g = ((2 * w + t) * 16 + l16) * 32 + quad * 8;
            bh[t] = ld_s8(&wehT_h[g]);
            bl[t] = ld_s8(&wehT_l[g]);
        }
#pragma unroll
        for (int mt = 0; mt < 4; ++mt) {
            const int base = (mt * 16 + l16) * 40 + quad * 8;
            const short8 ah = ld_s8(&efh[base]);
            const short8 al = ld_s8(&efl[base]);
#pragma unroll
            for (int t = 0; t < 2; ++t) {
                acc[mt][t] = __builtin_amdgcn_mfma_f32_16x16x32_bf16(ah, bh[t], acc[mt][t], 0, 0, 0);
                acc[mt][t] = __builtin_amdgcn_mfma_f32_16x16x32_bf16(ah, bl[t], acc[mt][t], 0, 0, 0);
                acc[mt][t] = __builtin_amdgcn_mfma_f32_16x16x32_bf16(al, bh[t], acc[mt][t], 0, 0, 0);
            }
        }
        // bias + relu + split -> ahi/alo
#pragma unroll
        for (int t = 0; t < 2; ++t) {
            const int col = (2 * w + t) * 16 + l16;
            const float bcol = be[col];
#pragma unroll
            for (int mt = 0; mt < 4; ++mt)
#pragma unroll
                for (int r = 0; r < 4; ++r) {
                    const int row = mt * 16 + quad * 4 + r;
                    const float v = fmaxf(acc[mt][t][r] + bcol, 0.f);
                    unsigned short h, lo;
                    split_bf(v, h, lo);
                    ahi[row * 136 + col] = h;
                    alo[row * 136 + col] = lo;
                }
        }
    }
    __syncthreads();

    // ---- mid GEMM: K=128, B direct from global, no barriers ----
#pragma unroll
    for (int mt = 0; mt < 4; ++mt)
#pragma unroll
        for (int t = 0; t < 2; ++t) acc[mt][t] = (float4v)0.f;

#pragma unroll
    for (int c = 0; c < 4; ++c) {
        const int k0 = c * 32;
        short8 bh[2], bl[2];
#pragma unroll
        for (int t = 0; t < 2; ++t) {
            const int g = ((2 * w + t) * 16 + l16) * 128 + k0 + quad * 8;
            bh[t] = ld_s8(&wmT_h[g]);
            bl[t] = ld_s8(&wmT_l[g]);
        }
#pragma unroll
        for (int mt = 0; mt < 4; ++mt) {
            const int base = (mt * 16 + l16) * 136 + k0 + quad * 8;
            const short8 ah = ld_s8(&ahi[base]);
            const short8 al = ld_s8(&alo[base]);
#pragma unroll
            for (int t = 0; t < 2; ++t) {
                acc[mt][t] = __builtin_amdgcn_mfma_f32_16x16x32_bf16(ah, bh[t], acc[mt][t], 0, 0, 0);
                acc[mt][t] = __builtin_amdgcn_mfma_f32_16x16x32_bf16(ah, bl[t], acc[mt][t], 0, 0, 0);
                acc[mt][t] = __builtin_amdgcn_mfma_f32_16x16x32_bf16(al, bh[t], acc[mt][t], 0, 0, 0);
            }
        }
    }
    __syncthreads();   // ahi/alo reads done; safe to overlay ms

    // ---- spill mid to ms[64][132] ----
#pragma unroll
    for (int mt = 0; mt < 4; ++mt)
#pragma unroll
        for (int t = 0; t < 2; ++t) {
            const int col = (2 * w + t) * 16 + l16;
#pragma unroll
            for (int r = 0; r < 4; ++r)
                ms[(mt * 16 + quad * 4 + r) * 132 + col] = acc[mt][t][r];
        }
    __syncthreads();

    // ---- epilogue: + bm + prefetched ps/pd, relu ----
    {
        const float4 bm4 = *(const float4*)&bm[4 * tx];
#pragma unroll
        for (int i = 0; i < 8; ++i) {
            const int row = 8 * ty + i;
            const int p = p0 + row;
            if (p < E) {
                float4 m4 = *(const float4*)&ms[row * 132 + 4 * tx];
                m4.x = fmaxf(m4.x + bm4.x + psr[i].x + pdr[i].x, 0.f);
                m4.y = fmaxf(m4.y + bm4.y + psr[i].y + pdr[i].y, 0.f);
                m4.z = fmaxf(m4.z + bm4.z + psr[i].z + pdr[i].z, 0.f);
                m4.w = fmaxf(m4.w + bm4.w + psr[i].w + pdr[i].w, 0.f);
                *(float4*)&ms[row * 132 + 4 * tx] = m4;
            }
        }
    }
    __syncthreads();

    // ---- run-length segmented reduction ----
    {
        const int j = tid & 127;
        const int base = (tid < 128) ? 0 : 32;
        float a = 0.f;
        for (int r = base; r < base + 32; ++r) {
            const int d = sdh[r];
            if (d < 0) break;
            a += ms[r * 132 + j];
            if (r == base + 31 || sdh[r + 1] != d) {
                atomicAdd(&agg[(size_t)d * 128 + j], a);
                a = 0.f;
            }
        }
    }
}

// ---- readout: one demand per wave, no in-loop barriers ----
__global__ __launch_bounds__(256) void readout_kernel(
    const float* __restrict__ Qs, const float* __restrict__ Qd,
    const float* __restrict__ df, const int* __restrict__ dp,
    const float* __restrict__ Wd, const float* __restrict__ b1,
    const float* __restrict__ w2, const float* __restrict__ b2,
    float* __restrict__ out, int D)
{
    __shared__ float wd[8 * 128];
    const int tid = threadIdx.x;
    const int wv = tid >> 6;
    const int l = tid & 63;
    for (int idx = tid; idx < 8 * 128; idx += 256) wd[idx] = Wd[idx];
    __syncthreads();
    const float b1a = b1[l], b1b = b1[l + 64];
    const float w2a = w2[l], w2b = w2[l + 64];
    const float bb = b2[0];
    for (int d = blockIdx.x * 4 + wv; d < D; d += gridDim.x * 4) {
        const int s = dp[2 * d], t = dp[2 * d + 1];
        float a = b1a + Qs[(size_t)s * 128 + l] + Qd[(size_t)t * 128 + l];
        float b = b1b + Qs[(size_t)s * 128 + l + 64] + Qd[(size_t)t * 128 + l + 64];
#pragma unroll
        for (int k = 0; k < 8; ++k) {
            const float f = df[(size_t)d * 8 + k];
            a = fmaf(f, wd[k * 128 + l], a);
            b = fmaf(f, wd[k * 128 + l + 64], b);
        }
        float v = fmaxf(a, 0.f) * w2a + fmaxf(b, 0.f) * w2b;
        for (int o = 32; o > 0; o >>= 1) v += __shfl_down(v, o);
        if (l == 0) out[d] = 1.f / (1.f + __expf(-(v + bb)));
    }
}

extern "C" void kernel_launch(void* const* d_in, const int* in_sizes, int n_in,
                              void* d_out, int out_size, void* d_ws, size_t ws_size,
                              hipStream_t stream)
{
    const float* node_feats   = (const float*)d_in[0];
    const float* edge_feats   = (const float*)d_in[1];
    const float* demand_feats = (const float*)d_in[2];
    const int*   ei = (const int*)d_in[3];
    const int*   dp = (const int*)d_in[4];
    const float* W_node = (const float*)d_in[5];
    const float* b_node = (const float*)d_in[6];
    const float* W_edge = (const float*)d_in[7];
    const float* b_edge = (const float*)d_in[8];
    const float* Wm[2] = {(const float*)d_in[9],  (const float*)d_in[13]};
    const float* bm[2] = {(const float*)d_in[10], (const float*)d_in[14]};
    const float* Wu[2] = {(const float*)d_in[11], (const float*)d_in[15]};
    const float* bu[2] = {(const float*)d_in[12], (const float*)d_in[16]};
    const float* W_r1 = (const float*)d_in[17];
    const float* b_r1 = (const float*)d_in[18];
    const float* W_r2 = (const float*)d_in[19];
    const float* b_r2 = (const float*)d_in[20];
    float* out = (float*)d_out;

    const int NN = in_sizes[0] / 32;   // 20000
    const int NE = in_sizes[3] / 2;    // 640000
    const int ND = in_sizes[4] / 2;    // 100000

    float* B0 = (float*)d_ws;
    float* B1 = B0 + (size_t)NN * 128;
    float* B2 = B1 + (size_t)NN * 128;
    float* B3 = B2 + (size_t)NN * 128;
    int* cnt  = (int*)(B3 + (size_t)NN * 128);
    int* fill = cnt + NN;
    int* perm = fill + NN;
    int* ssrc = perm + NE;
    int* sdst = ssrc + NE;
    unsigned short* wehT_h = (unsigned short*)(sdst + NE);
    unsigned short* wehT_l = wehT_h + 128 * 32;
    unsigned short* wm0_h  = wehT_l + 128 * 32;
    unsigned short* wm0_l  = wm0_h + 128 * 128;
    unsigned short* wm1_h  = wm0_l + 128 * 128;
    unsigned short* wm1_l  = wm1_h + 128 * 128;

    const int nbN = (NN + 63) / 64;
    const int nbE = (NE + 63) / 64;

    // ---- weight prep ----
    tsplit_kernel<<<16, 256, 0, stream>>>(W_edge, 16, 128, 32, wehT_h, wehT_l);
    tsplit_kernel<<<64, 256, 0, stream>>>(Wm[0] + 128 * 128, 128, 128, 128, wm0_h, wm0_l);
    tsplit_kernel<<<64, 256, 0, stream>>>(Wm[1] + 128 * 128, 128, 128, 128, wm1_h, wm1_l);

    // ---- sort edges by dst ----
    hipMemsetAsync(cnt, 0, NN * sizeof(int), stream);
    hist_kernel<<<(NE + 255) / 256, 256, 0, stream>>>(ei, cnt, NE);
    scan_kernel<<<1, 256, 0, stream>>>(cnt, fill, NN);
    scatter_kernel<<<(NE + 255) / 256, 256, 0, stream>>>(ei, fill, perm, ssrc, sdst, NE);

    encode_nodes_kernel<<<512, 256, 0, stream>>>(node_feats, W_node, b_node, B0, NN);

    // ---- layer 0: hin=B0 ----
    sgemm_dual_kernel<<<nbN, 256, 0, stream>>>(B0, Wm[0], Wm[0] + 256 * 128, B1, B2, NN);
    hipMemsetAsync(B3, 0, (size_t)NN * 128 * sizeof(float), stream);
    edge_msg_mfma_kernel<<<nbE, 256, 0, stream>>>(edge_feats, perm, ssrc, sdst,
                                                  wehT_h, wehT_l, b_edge,
                                                  wm0_h, wm0_l, bm[0], B1, B2, B3, NE);
    sgemm_kernel<<<nbN, 256, 0, stream>>>(B0, B3, Wu[0], bu[0], B1, NN, 256, 1);

    // ---- layer 1: hin=B1 ----
    sgemm_dual_kernel<<<nbN, 256, 0, stream>>>(B1, Wm[1], Wm[1] + 256 * 128, B0, B2, NN);
    hipMemsetAsync(B3, 0, (size_t)NN * 128 * sizeof(float), stream);
    edge_msg_mfma_kernel<<<nbE, 256, 0, stream>>>(edge_feats, perm, ssrc, sdst,
                                                  wehT_h, wehT_l, b_edge,
                                                  wm1_h, wm1_l, bm[1], B0, B2, B3, NE);
    sgemm_kernel<<<nbN, 256, 0, stream>>>(B1, B3, Wu[1], bu[1], B2, NN, 256, 1);

    // ---- readout ----
    sgemm_dual_kernel<<<nbN, 256, 0, stream>>>(B2, W_r1, W_r1 + 128 * 128, B0, B1, NN);
    readout_kernel<<<2048, 256, 0, stream>>>(B0, B1, demand_feats, dp,
                                             W_r1 + 256 * 128, b_r1, W_r2, b_r2, out, ND);
}